// Round 3
// baseline (449.137 us; speedup 1.0000x reference)
//
#include <hip/hip_runtime.h>
#include <math.h>

#define NN_NODES 4096
#define D_IN 128
#define D_H 256
#define KTOP 17
#define NEDGE (NN_NODES * KTOP)
#define INV_TEMP 5.0f
#define EPSV 1e-8f
#define CCAP 1024

typedef __bf16 bf16x8 __attribute__((ext_vector_type(8)));
typedef float f32x4 __attribute__((ext_vector_type(4)));

// ---------------- helpers ----------------
__device__ __forceinline__ float block_reduce_sum(float v, float* sb) {
#pragma unroll
    for (int o = 32; o > 0; o >>= 1) v += __shfl_down(v, o, 64);
    int wid = threadIdx.x >> 6;
    __syncthreads();
    if ((threadIdx.x & 63) == 0) sb[wid] = v;
    __syncthreads();
    return sb[0] + sb[1] + sb[2] + sb[3];
}

// fp32 -> bf16 (RNE)
__device__ __forceinline__ unsigned short f2bf(float x) {
    unsigned u = __float_as_uint(x);
    unsigned r = u + 0x7fff + ((u >> 16) & 1);
    return (unsigned short)(r >> 16);
}

// bf16 pair unpack (stored as 2x u16 in a u32)
__device__ __forceinline__ float bflo(unsigned x) { return __uint_as_float(x << 16); }
__device__ __forceinline__ float bfhi(unsigned x) { return __uint_as_float(x & 0xffff0000u); }

__device__ __forceinline__ float dot8bf(uint4 a, uint4 b) {
    float s = bflo(a.x) * bflo(b.x) + bfhi(a.x) * bfhi(b.x);
    s += bflo(a.y) * bflo(b.y) + bfhi(a.y) * bfhi(b.y);
    s += bflo(a.z) * bflo(b.z) + bfhi(a.z) * bfhi(b.z);
    s += bflo(a.w) * bflo(b.w) + bfhi(a.w) * bfhi(b.w);
    return s;
}

// async global -> LDS, 16 bytes per lane. lds dest must be wave-uniform base;
// HW deposits at base + lane*16. global address is per-lane.
__device__ __forceinline__ void gl_lds16(const void* g, void* l) {
    __builtin_amdgcn_global_load_lds(
        (const __attribute__((address_space(1))) void*)(g),
        (__attribute__((address_space(3))) void*)(l), 16, 0, 0);
}

// ---------------- elementwise / setup ----------------
__global__ __launch_bounds__(256) void zero_f(float* p, int n) {
    int i = blockIdx.x * 256 + threadIdx.x;
    if (i < n) p[i] = 0.f;
}

__global__ __launch_bounds__(256) void zero_i(int* p, int n) {
    int i = blockIdx.x * 256 + threadIdx.x;
    if (i < n) p[i] = 0;
}

__global__ __launch_bounds__(256) void x1_kernel(const float* __restrict__ x,
                                                 const float* __restrict__ p_feat,
                                                 const float* __restrict__ p_shared,
                                                 float* __restrict__ x1) {
    int i = blockIdx.x * 256 + threadIdx.x;
    if (i >= NN_NODES * D_IN) return;
    int c = i & (D_IN - 1);
    float v = x[i] * p_feat[c];
    v = fmaxf(v, 0.0f) * p_shared[c];
    x1[i] = v;
}

// dinv[i] = rsqrt(1 + indegree[i])
__global__ __launch_bounds__(256) void to_dinv(const int* __restrict__ cnt, float* __restrict__ dinv) {
    int i = blockIdx.x * 256 + threadIdx.x;
    if (i < NN_NODES) dinv[i] = rsqrtf(1.0f + (float)cnt[i]);
}

// ---------------- input-graph CSR (keyed by dst) ----------------
__global__ __launch_bounds__(256) void ecount_kernel(const int* __restrict__ dst, int* __restrict__ cnt, int E) {
    int e = blockIdx.x * 256 + threadIdx.x;
    if (e < E) atomicAdd(&cnt[dst[e]], 1);
}

__global__ __launch_bounds__(256) void efill_kernel(const int* __restrict__ src, const int* __restrict__ dst,
                                                    const int* __restrict__ ptr, int* __restrict__ cnt,
                                                    int* __restrict__ esrt, int E) {
    int e = blockIdx.x * 256 + threadIdx.x;
    if (e >= E) return;
    int d = dst[e];
    int p = ptr[d] + atomicAdd(&cnt[d], 1);
    esrt[p] = src[e];
}

// out[n][c] = act( dinv[n]^2*h[n][c] + sum_{edges s->n} dinv[s]*dinv[n]*h[s][c] + bias[c] )
__global__ void prop_gather(float* __restrict__ out, const float* __restrict__ h,
                            const float* __restrict__ dinv, const int* __restrict__ eptr,
                            const int* __restrict__ esrt, const float* __restrict__ bias,
                            int C, int act) {
    int n = blockIdx.x, t = threadIdx.x;
    float dn = dinv[n];
    float acc = dn * dn * h[(size_t)n * C + t];
    int p1 = eptr[n + 1];
    for (int p = eptr[n]; p < p1; ++p) {
        int s = esrt[p];
        acc += dinv[s] * dn * h[(size_t)s * C + t];
    }
    if (bias) acc += bias[t];
    if (act == 1) acc = fmaxf(acc, 0.f);
    else if (act == 2) acc = acc > 0.f ? acc : expm1f(acc);
    out[(size_t)n * C + t] = acc;
}

// h = concat(x1, agg)*p_balance; hn = h/(||h||+eps) -> bf16
__global__ __launch_bounds__(256) void h_hn_kernel(const float* __restrict__ x1,
                                                   const float* __restrict__ agg,
                                                   const float* __restrict__ p_balance,
                                                   unsigned short* __restrict__ hn_bf) {
    __shared__ float sb[4];
    int n = blockIdx.x, t = threadIdx.x;
    float v;
    if (t < D_IN) v = x1[(size_t)n * D_IN + t] * p_balance[t];
    else v = agg[(size_t)n * D_IN + (t - D_IN)] * p_balance[t];
    float ss = block_reduce_sum(v * v, sb);
    float inv = 1.0f / (sqrtf(ss) + EPSV);
    hn_bf[(size_t)n * D_H + t] = f2bf(v * inv);
}

// row normalize two Z buffers -> bf16 in one launch (grid 2*NN_NODES)
__global__ __launch_bounds__(256) void rownorm2_kernel(const float* __restrict__ Z1,
                                                       unsigned short* __restrict__ z1bf,
                                                       const float* __restrict__ Z2,
                                                       unsigned short* __restrict__ z2bf) {
    __shared__ float sb[4];
    int b = blockIdx.x, t = threadIdx.x;
    const float* Z = (b < NN_NODES) ? Z1 : Z2;
    unsigned short* zbf = (b < NN_NODES) ? z1bf : z2bf;
    int n = (b < NN_NODES) ? b : b - NN_NODES;
    float v = Z[(size_t)n * D_H + t];
    float ss = block_reduce_sum(v * v, sb);
    float inv = 1.0f / (sqrtf(ss) + EPSV);
    zbf[(size_t)n * D_H + t] = f2bf(v * inv);
}

// diag[i] = dot(z1n[i], z2n[i])  (one wave per row)
__global__ __launch_bounds__(256) void diag_kernel(const unsigned short* __restrict__ z1,
                                                   const unsigned short* __restrict__ z2,
                                                   float* __restrict__ diag) {
    int row = blockIdx.x * 4 + (threadIdx.x >> 6);
    int lane = threadIdx.x & 63;
    uint2 ua = *(const uint2*)&z1[(size_t)row * D_H + lane * 4];
    uint2 ub = *(const uint2*)&z2[(size_t)row * D_H + lane * 4];
    float s = bflo(ua.x) * bflo(ub.x) + bfhi(ua.x) * bfhi(ub.x) +
              bflo(ua.y) * bflo(ub.y) + bfhi(ua.y) * bfhi(ub.y);
#pragma unroll
    for (int o = 32; o > 0; o >>= 1) s += __shfl_down(s, o, 64);
    if (lane == 0) diag[row] = s;
}

// ---------------- fp32 GEMM (small NN cases) ----------------
#define BM 64
#define BN 64
#define BK 16

__global__ __launch_bounds__(256) void gemm_nn_kernel(const float* __restrict__ A,
                                                      const float* __restrict__ B,
                                                      float* __restrict__ C, int M, int Nn,
                                                      int Kk, const float* __restrict__ bias,
                                                      int ep) {
    __shared__ float As[BK][BM + 4];
    __shared__ float Bs[BK][BN + 4];
    const int tid = threadIdx.x;
    const int tx = tid & 15, ty = tid >> 4;
    const int m0 = blockIdx.y * BM, n0 = blockIdx.x * BN;
    const int arow = tid >> 2, acol = (tid & 3) << 2;
    const int brow = tid >> 4, bcol = (tid & 15) << 2;
    float acc[4][4] = {{0.f}};

    for (int k0 = 0; k0 < Kk; k0 += BK) {
        float4 av = *(const float4*)&A[(size_t)(m0 + arow) * Kk + k0 + acol];
        float4 bv = *(const float4*)&B[(size_t)(k0 + brow) * Nn + n0 + bcol];
        As[acol + 0][arow] = av.x;
        As[acol + 1][arow] = av.y;
        As[acol + 2][arow] = av.z;
        As[acol + 3][arow] = av.w;
        *(float4*)&Bs[brow][bcol] = bv;
        __syncthreads();
#pragma unroll
        for (int k = 0; k < BK; ++k) {
            float4 a = *(const float4*)&As[k][ty << 2];
            float4 b = *(const float4*)&Bs[k][tx << 2];
            acc[0][0] += a.x * b.x; acc[0][1] += a.x * b.y; acc[0][2] += a.x * b.z; acc[0][3] += a.x * b.w;
            acc[1][0] += a.y * b.x; acc[1][1] += a.y * b.y; acc[1][2] += a.y * b.z; acc[1][3] += a.y * b.w;
            acc[2][0] += a.z * b.x; acc[2][1] += a.z * b.y; acc[2][2] += a.z * b.z; acc[2][3] += a.z * b.w;
            acc[3][0] += a.w * b.x; acc[3][1] += a.w * b.y; acc[3][2] += a.w * b.z; acc[3][3] += a.w * b.w;
        }
        __syncthreads();
    }
    float bb[4] = {0.f, 0.f, 0.f, 0.f};
    if (ep) {
#pragma unroll
        for (int j = 0; j < 4; ++j) bb[j] = bias[n0 + (tx << 2) + j];
    }
#pragma unroll
    for (int i = 0; i < 4; ++i) {
        int m = m0 + (ty << 2) + i;
        float r[4];
#pragma unroll
        for (int j = 0; j < 4; ++j) {
            float v = acc[i][j] + bb[j];
            if (ep == 1) v = fmaxf(v, 0.0f);
            else if (ep == 2) v = v > 0.0f ? v : expm1f(v);
            r[j] = v;
        }
        *(float4*)&C[(size_t)m * Nn + n0 + (tx << 2)] = *(float4*)r;
    }
}

// ---------------- MFMA NT GEMM: C[4096,4096] = X @ Y^T, K=256, single bf16 ----------------
// Full-K panel staging: A-panel (128 rows x 256 cols bf16 = 64 KB) is CONTIGUOUS in
// global memory, staged with linear gl_lds16 (1 KB contiguous per wave-instruction,
// 8 cache lines/instr vs 64 scattered segments before). XOR swizzle (chunk bits 4-6
// ^= row&7) applied to the GLOBAL source address (within-row permutation, coalescing
// preserved) and identically on ds_read -> conflict-free fragment reads.
// C may be nullptr (zrow-only pass).
__global__ __launch_bounds__(256) void gemm_nt_mfma(const unsigned short* __restrict__ Abf,
                                                    const unsigned short* __restrict__ Bbf,
                                                    float* __restrict__ C,
                                                    float* __restrict__ zrow) {
    __shared__ unsigned short lds[65536];  // A panel 64 KB + B panel 64 KB = 128 KB
    const int tid = threadIdx.x;
    const int w = tid >> 6, lane = tid & 63;
    const int m0 = blockIdx.y * 128, n0 = blockIdx.x * 128;
    const int wmt = (w >> 1) * 4;
    const int wnt = (w & 1) * 4;
    const int lrow = lane & 15, lquad = lane >> 4;

    f32x4 acc[4][4];
#pragma unroll
    for (int i = 0; i < 4; ++i)
#pragma unroll
        for (int j = 0; j < 4; ++j) acc[i][j] = (f32x4)(0.f);

    char* Ap = (char*)lds;            // [128][256] bf16, swizzled
    char* Bp = (char*)lds + 65536;
    const char* Ag = (const char*)Abf + (size_t)m0 * 512;  // contiguous 64 KB panel
    const char* Bg = (const char*)Bbf + (size_t)n0 * 512;

    // stage both panels: 16 wave-instructions per panel per wave, linear LDS dest,
    // swizzled global source (involution on bits 4-6 keyed by row bits 9-11).
#pragma unroll
    for (int ti = 0; ti < 16; ++ti) {
        int lb = (ti * 4 + w) * 1024;          // wave-uniform 1 KB chunk base
        int lbyte = lb + lane * 16;            // linear per-lane LDS byte
        int gbyte = lbyte ^ (((lbyte >> 9) & 7) << 4);
        gl_lds16(Ag + gbyte, Ap + lb);
        gl_lds16(Bg + gbyte, Bp + lb);
    }
    __syncthreads();

    // fragment read: logical A[row][k0..k0+8) lives at swizzled byte offset
    auto rdfrag = [&](const char* P, int rt, int ks) -> bf16x8 {
        int row = rt * 16 + lrow;
        int byte = row * 512 + ks * 64 + lquad * 16;
        byte ^= ((row & 7) << 4);
        return __builtin_bit_cast(bf16x8, *(const uint4*)(P + byte));
    };

#pragma unroll
    for (int ks = 0; ks < 8; ++ks) {
        bf16x8 a[4], b[4];
#pragma unroll
        for (int i = 0; i < 4; ++i) {
            a[i] = rdfrag(Ap, wmt + i, ks);
            b[i] = rdfrag(Bp, wnt + i, ks);
        }
#pragma unroll
        for (int i = 0; i < 4; ++i)
#pragma unroll
            for (int j = 0; j < 4; ++j)
                acc[i][j] = __builtin_amdgcn_mfma_f32_16x16x32_bf16(a[i], b[j], acc[i][j], 0, 0, 0);
    }

    const int rq = (lane >> 4) * 4;
    if (C) {
        const int c0 = lane & 3;
        const int cg = ((lane & 15) >> 2) << 2;  // 4-col group base within 16-col tile
#pragma unroll
        for (int i = 0; i < 4; ++i) {
            int row = m0 + (wmt + i) * 16 + rq + c0;
#pragma unroll
            for (int j = 0; j < 4; ++j) {
                float a0 = acc[i][j][0], a1 = acc[i][j][1], a2 = acc[i][j][2], a3 = acc[i][j][3];
                // 4x4 transpose across (lane-quad, reg): stage 1 (xor 1)
                float x0 = __shfl_xor(a1, 1, 64), x1 = __shfl_xor(a0, 1, 64);
                float x2 = __shfl_xor(a3, 1, 64), x3 = __shfl_xor(a2, 1, 64);
                bool odd = (c0 & 1) != 0;
                float t0 = odd ? x0 : a0;
                float t1 = odd ? a1 : x1;
                float t2 = odd ? x2 : a2;
                float t3 = odd ? a3 : x3;
                // stage 2 (xor 2)
                float y0 = __shfl_xor(t2, 2, 64), y2 = __shfl_xor(t0, 2, 64);
                float y1 = __shfl_xor(t3, 2, 64), y3 = __shfl_xor(t1, 2, 64);
                bool hi = (c0 & 2) != 0;
                f32x4 o;
                o[0] = hi ? y0 : t0;
                o[1] = hi ? y1 : t1;
                o[2] = hi ? t2 : y2;
                o[3] = hi ? t3 : y3;
                int cb = n0 + (wnt + j) * 16 + cg;
                *(f32x4*)&C[(size_t)row * NN_NODES + cb] = o;
            }
        }
    }
    if (zrow) {
#pragma unroll
        for (int i = 0; i < 4; ++i) {
            int rb = m0 + (wmt + i) * 16 + rq;
#pragma unroll
            for (int r = 0; r < 4; ++r) {
                float s = 0.f;
#pragma unroll
                for (int j = 0; j < 4; ++j) s += __expf(INV_TEMP * acc[i][j][r]);
#pragma unroll
                for (int o = 1; o < 16; o <<= 1) s += __shfl_xor(s, o, 64);
                if ((lane & 15) == 0) atomicAdd(&zrow[rb + r], s);
            }
        }
    }
}

// ---------------- top-k: threshold prefilter + rank-based selection ----------------
__global__ __launch_bounds__(256) void topk_kernel(const float* __restrict__ S,
                                                   float* __restrict__ vals,
                                                   int* __restrict__ idxo) {
    __shared__ float sm[256];
    __shared__ int ccnt;
    __shared__ float cv[CCAP];
    __shared__ int ci[CCAP];
    __shared__ float wvs[8];
    __shared__ int wis[8];
    const int i = blockIdx.x, t = threadIdx.x;
    const int lane = t & 63, wid = t >> 6;
    const float* row = &S[(size_t)i * NN_NODES];
    float v[16];
    int id[16];
#pragma unroll
    for (int u = 0; u < 4; ++u) {
        int base = u * 1024 + t * 4;
        float4 f = *(const float4*)&row[base];
        v[u * 4 + 0] = f.x; id[u * 4 + 0] = base + 0;
        v[u * 4 + 1] = f.y; id[u * 4 + 1] = base + 1;
        v[u * 4 + 2] = f.z; id[u * 4 + 2] = base + 2;
        v[u * 4 + 3] = f.w; id[u * 4 + 3] = base + 3;
    }
    float m = v[0];
#pragma unroll
    for (int u = 1; u < 16; ++u) m = fmaxf(m, v[u]);
    sm[t] = m;
    if (t == 0) ccnt = 0;
    __syncthreads();

    // every wave: T = 17th-largest of 64 group maxima (rank via shfl loop)
    float g = fmaxf(fmaxf(sm[lane * 4 + 0], sm[lane * 4 + 1]),
                    fmaxf(sm[lane * 4 + 2], sm[lane * 4 + 3]));
    int rank = 0;
#pragma unroll
    for (int o = 1; o < 64; ++o) {
        float ov = __shfl_xor(g, o, 64);
        int ol = lane ^ o;
        if (ov > g || (ov == g && ol < lane)) rank++;
    }
    unsigned long long ball = __ballot(rank == 16);
    int tl = __ffsll((long long)ball) - 1;
    const float T = __shfl(g, tl, 64);

    // emit candidates >= T
#pragma unroll
    for (int u = 0; u < 16; ++u) {
        if (v[u] >= T) {
            int p = atomicAdd(&ccnt, 1);
            if (p < CCAP) { cv[p] = v[u]; ci[p] = id[u]; }
        }
    }
    __syncthreads();
    const int cnt = ccnt;

    if (cnt <= CCAP) {
        for (int p = t; p < cnt; p += 256) {
            float mv = cv[p];
            int mi = ci[p];
            int r = 0;
            for (int q = 0; q < cnt; ++q) {
                float qv = cv[q];
                int qi = ci[q];
                if (qv > mv || (qv == mv && qi < mi)) r++;
            }
            if (r < KTOP) {
                vals[i * KTOP + r] = isnan(mv) ? 0.f : mv;
                idxo[i * KTOP + r] = mi;
            }
        }
    } else {
        float bv = v[0];
        int bi = id[0];
#pragma unroll
        for (int u = 1; u < 16; ++u)
            if (v[u] > bv || (v[u] == bv && id[u] < bi)) { bv = v[u]; bi = id[u]; }
        for (int k = 0; k < KTOP; ++k) {
            float mv = bv;
            int mi = bi;
#pragma unroll
            for (int o = 1; o < 64; o <<= 1) {
                float ov = __shfl_xor(mv, o, 64);
                int oi = __shfl_xor(mi, o, 64);
                if (ov > mv || (ov == mv && oi < mi)) { mv = ov; mi = oi; }
            }
            int slot = ((k & 1) << 2) + wid;
            if (lane == 0) { wvs[slot] = mv; wis[slot] = mi; }
            __syncthreads();
            int b0 = (k & 1) << 2;
            mv = wvs[b0]; mi = wis[b0];
#pragma unroll
            for (int ww = 1; ww < 4; ++ww) {
                float ov = wvs[b0 + ww];
                int oi = wis[b0 + ww];
                if (ov > mv || (ov == mv && oi < mi)) { mv = ov; mi = oi; }
            }
            if (t == 0) {
                vals[i * KTOP + k] = isnan(mv) ? 0.f : mv;
                idxo[i * KTOP + k] = mi;
            }
            if (bi == mi) {
#pragma unroll
                for (int u = 0; u < 16; ++u)
                    if (id[u] == mi) v[u] = -INFINITY;
                bv = v[0]; bi = id[0];
#pragma unroll
                for (int u = 1; u < 16; ++u)
                    if (v[u] > bv || (v[u] == bv && id[u] < bi)) { bv = v[u]; bi = id[u]; }
            }
        }
    }
}

// ---------------- sparse W construction ----------------
__global__ __launch_bounds__(256) void count_indeg(const int* __restrict__ idx, int* __restrict__ cnt) {
    int e = blockIdx.x * 256 + threadIdx.x;
    if (e < NEDGE) atomicAdd(&cnt[idx[e]], 1);
}

__global__ __launch_bounds__(256) void scan_kernel(int* __restrict__ cnt, int* __restrict__ ptr) {
    __shared__ int tmp[256];
    int t = threadIdx.x;
    int base = t * 16;
    int local[16]; int s = 0;
#pragma unroll
    for (int u = 0; u < 16; ++u) { local[u] = s; s += cnt[base + u]; }
#pragma unroll
    for (int u = 0; u < 16; ++u) cnt[base + u] = 0;
    tmp[t] = s;
    __syncthreads();
    for (int off = 1; off < 256; off <<= 1) {
        int v = (t >= off) ? tmp[t - off] : 0;
        __syncthreads();
        tmp[t] += v;
        __syncthreads();
    }
    int prefix = (t > 0) ? tmp[t - 1] : 0;
#pragma unroll
    for (int u = 0; u < 16; ++u) ptr[base + u] = prefix + local[u];
    if (t == 255) ptr[NN_NODES] = prefix + s;
}

__global__ __launch_bounds__(256) void fill_rev(const int* __restrict__ idx, const float* __restrict__ vals,
                                                const int* __restrict__ ptr, int* __restrict__ fcnt,
                                                int* __restrict__ rrow, int* __restrict__ rsrc,
                                                float* __restrict__ rval) {
    int e = blockIdx.x * 256 + threadIdx.x;
    if (e >= NEDGE) return;
    int i = e / KTOP;
    int j = idx[e];
    int p = ptr[j] + atomicAdd(&fcnt[j], 1);
    rrow[p] = j; rsrc[p] = i; rval[p] = vals[e];
}

// fused fwd+rev edge weights (grid covers 2*NEDGE)
__global__ __launch_bounds__(256) void wedges_kernel(const int* __restrict__ idx, const float* __restrict__ vals,
                                                     const int* __restrict__ rrow, const int* __restrict__ rsrc,
                                                     const float* __restrict__ rval,
                                                     float* __restrict__ wfwd, float* __restrict__ wrev) {
    int e = blockIdx.x * 256 + threadIdx.x;
    if (e < NEDGE) {
        int i = e / KTOP;
        int j = idx[e];
        float a = vals[e];
        float c = 1.0f;
        const int* lj = &idx[j * KTOP];
#pragma unroll
        for (int k = 0; k < KTOP; ++k)
            if (lj[k] == i) { a += vals[j * KTOP + k]; c = 2.0f; }
        float w = a / c;
        wfwd[e] = w > 0.f ? w : 0.f;
    } else if (e < 2 * NEDGE) {
        int e2 = e - NEDGE;
        int i = rrow[e2], s = rsrc[e2];
        const int* li = &idx[i * KTOP];
        bool dup = false;
#pragma unroll
        for (int k = 0; k < KTOP; ++k)
            if (li[k] == s) dup = true;
        wrev[e2] = dup ? 0.f : fmaxf(rval[e2], 0.f);
    }
}

// out[i,:] = act(sum_j W[i,j]*X[j,:] + bias)
__global__ __launch_bounds__(256) void spmm_kernel(float* __restrict__ out, const float* __restrict__ X,
                                                   const int* __restrict__ idx, const float* __restrict__ wfwd,
                                                   const int* __restrict__ ptr, const int* __restrict__ rsrc,
                                                   const float* __restrict__ wrev,
                                                   const float* __restrict__ bias, int act) {
    int i = blockIdx.x, c = threadIdx.x;
    float acc = 0.f;
#pragma unroll
    for (int k = 0; k < KTOP; ++k) {
        int j = idx[i * KTOP + k];
        float w = wfwd[i * KTOP + k];
        acc += w * X[(size_t)j * D_H + c];
    }
    int p1 = ptr[i + 1];
    for (int p = ptr[i]; p < p1; ++p) {
        float w = wrev[p];
        if (w != 0.f) acc += w * X[(size_t)rsrc[p] * D_H + c];
    }
    acc += bias[c];
    if (act == 1) acc = fmaxf(acc, 0.f);
    else acc = acc > 0.f ? acc : expm1f(acc);
    out[(size_t)i * D_H + c] = acc;
}

// fused pf/pb over fwd+rev lists; S entries recomputed as bf16 dots (16 lanes/edge)
__global__ __launch_bounds__(256) void pfpb_edges(const unsigned short* __restrict__ z1,
                                                  const unsigned short* __restrict__ z2,
                                                  const int* __restrict__ idx,
                                                  const float* __restrict__ wfwd,
                                                  const int* __restrict__ rrow,
                                                  const int* __restrict__ rsrc,
                                                  const float* __restrict__ wrev,
                                                  const float* __restrict__ zrow,
                                                  float* __restrict__ pf, float* __restrict__ pb) {
    int g = (blockIdx.x * 256 + threadIdx.x) >> 4;  // edge id
    int l = threadIdx.x & 15;
    if (g >= 2 * NEDGE) return;
    int i, j;
    float wv;
    if (g < NEDGE) { i = g / KTOP; j = idx[g]; wv = wfwd[g]; }
    else { int e2 = g - NEDGE; i = rrow[e2]; j = rsrc[e2]; wv = wrev[e2]; }
    if (wv == 0.f) return;
    // lane l covers dims [16*l, 16*l+16)
    const uint4* a1 = (const uint4*)&z1[(size_t)i * D_H + l * 16];
    const uint4* b1 = (const uint4*)&z2[(size_t)j * D_H + l * 16];
    const uint4* a2 = (const uint4*)&z1[(size_t)j * D_H + l * 16];
    const uint4* b2 = (const uint4*)&z2[(size_t)i * D_H + l * 16];
    float s1 = dot8bf(a1[0], b1[0]) + dot8bf(a1[1], b1[1]);  // S[i][j]
    float s2 = dot8bf(a2[0], b2[0]) + dot8bf(a2[1], b2[1]);  // S[j][i]
#pragma unroll
    for (int o = 8; o > 0; o >>= 1) {
        s1 += __shfl_xor(s1, o, 64);
        s2 += __shfl_xor(s2, o, 64);
    }
    if (l == 0) {
        float pfv = expf(s1 * INV_TEMP) / zrow[i] * wv;
        float pbv = expf(s2 * INV_TEMP) / zrow[j] * wv;
        atomicAdd(&pf[i], pfv);
        atomicAdd(&pb[i], pbv);
    }
}

__global__ __launch_bounds__(256) void loss_kernel(const float* __restrict__ diag,
                                                   const float* __restrict__ zrow,
                                                   const float* __restrict__ pf,
                                                   const float* __restrict__ pb,
                                                   float* __restrict__ out) {
    __shared__ float sb[4];
    int t = threadIdx.x;
    float s = 0.f;
    for (int i = t; i < NN_NODES; i += 256) {
        float p = expf(INV_TEMP * diag[i]) / zrow[i];
        s += -logf(fmaxf(p, EPSV));
        s += 0.5f * (-logf(fmaxf(pf[i], EPSV)) - logf(fmaxf(pb[i], EPSV)));
    }
    float tot = block_reduce_sum(s, sb);
    if (t == 0) out[0] = tot / (float)NN_NODES;
}

// ---------------- launch ----------------
extern "C" void kernel_launch(void* const* d_in, const int* in_sizes, int n_in,
                              void* d_out, int out_size, void* d_ws, size_t ws_size,
                              hipStream_t stream) {
    (void)n_in; (void)out_size; (void)ws_size;
    const float* x = (const float*)d_in[0];
    const int* esrc = (const int*)d_in[1];
    const int* edst = (const int*)d_in[2];
    const float* p_feat = (const float*)d_in[3];
    const float* p_shared = (const float*)d_in[4];
    const float* p_balance = (const float*)d_in[5];
    const float* W1 = (const float*)d_in[6];
    const float* b1 = (const float*)d_in[7];
    const float* W2 = (const float*)d_in[8];
    const float* b2 = (const float*)d_in[9];
    const int E = in_sizes[1];

    float* ws = (float*)d_ws;
    size_t off = 0;
    float* SIM = ws + off; off += (size_t)NN_NODES * NN_NODES;
    float* X1  = ws + off; off += (size_t)NN_NODES * D_IN;
    float* AGG = ws + off; off += (size_t)NN_NODES * D_IN;
    float* T1  = ws + off; off += (size_t)NN_NODES * D_H;
    float* H1  = ws + off; off += (size_t)NN_NODES * D_H;
    float* T2  = ws + off; off += (size_t)NN_NODES * D_H;
    float* Z1  = ws + off; off += (size_t)NN_NODES * D_H;
    float* G1  = ws + off; off += (size_t)NN_NODES * D_H;
    float* Z2  = ws + off; off += (size_t)NN_NODES * D_H;
    float* DINV = ws + off; off += NN_NODES;
    float* VALS = ws + off; off += (size_t)NEDGE;
    int*   IDX  = (int*)(ws + off); off += (size_t)NEDGE;
    float* WFWD = ws + off; off += (size_t)NEDGE;
    int*   RPTR = (int*)(ws + off); off += NN_NODES + 1;
    int*   FCNT = (int*)(ws + off); off += NN_NODES;
    int*   RROW = (int*)(ws + off); off += (size_t)NEDGE;
    int*   RSRC = (int*)(ws + off); off += (size_t)NEDGE;
    float* RVAL = ws + off; off += (size_t)NEDGE;
    float* WREV = ws + off; off += (size_t)NEDGE;
    float* ZROW = ws + off; off += NN_NODES;   // ZROW,PF,PB contiguous (zeroed together)
    float* PF = ws + off; off += NN_NODES;
    float* PB = ws + off; off += NN_NODES;
    float* DIAG = ws + off; off += NN_NODES;
    unsigned short* HNbf = (unsigned short*)(ws + off); off += (size_t)NN_NODES * D_H / 2;
    unsigned short* Z1bf = (unsigned short*)(ws + off); off += (size_t)NN_NODES * D_H / 2;
    unsigned short* Z2bf = (unsigned short*)(ws + off); off += (size_t)NN_NODES * D_H / 2;
    int* ECNT = (int*)(ws + off); off += NN_NODES;
    int* EPTR = (int*)(ws + off); off += NN_NODES + 1;
    int* ESRT = (int*)(ws + off); off += (size_t)E;

    const int EB = (NEDGE + 255) / 256;
    const int NB = (NN_NODES + 255) / 256;
    const int EBi = (E + 255) / 256;

    // 1. x1
    x1_kernel<<<(NN_NODES * D_IN + 255) / 256, 256, 0, stream>>>(x, p_feat, p_shared, X1);
    // 2. input-graph CSR + dinv (deg = 1 + indegree)
    zero_i<<<NB, 256, 0, stream>>>(ECNT, NN_NODES);
    ecount_kernel<<<EBi, 256, 0, stream>>>(edst, ECNT, E);
    to_dinv<<<NB, 256, 0, stream>>>(ECNT, DINV);
    scan_kernel<<<1, 256, 0, stream>>>(ECNT, EPTR);  // zeroes ECNT for efill
    efill_kernel<<<EBi, 256, 0, stream>>>(esrc, edst, EPTR, ECNT, ESRT, E);
    // zero ZROW/PF/PB (contiguous)
    zero_f<<<(3 * NN_NODES + 255) / 256, 256, 0, stream>>>(ZROW, 3 * NN_NODES);
    // 3. agg = A_norm @ x1  (gather)
    prop_gather<<<NN_NODES, D_IN, 0, stream>>>(AGG, X1, DINV, EPTR, ESRT, nullptr, D_IN, 0);
    // 4. h, hn (bf16)
    h_hn_kernel<<<NN_NODES, 256, 0, stream>>>(X1, AGG, p_balance, HNbf);
    // 5. sim = hn @ hn^T  (MFMA bf16, full-K panel staging)
    {
        dim3 g(NN_NODES / 128, NN_NODES / 128);
        gemm_nt_mfma<<<g, 256, 0, stream>>>(HNbf, HNbf, SIM, nullptr);
    }
    // 6. topk (threshold prefilter + rank selection)
    topk_kernel<<<NN_NODES, 256, 0, stream>>>(SIM, VALS, IDX);
    // 7. sparse W: reverse CSR + fused edge weights
    zero_i<<<NB, 256, 0, stream>>>(FCNT, NN_NODES);
    count_indeg<<<EB, 256, 0, stream>>>(IDX, FCNT);
    scan_kernel<<<1, 256, 0, stream>>>(FCNT, RPTR);  // zeroes FCNT for fill_rev
    fill_rev<<<EB, 256, 0, stream>>>(IDX, VALS, RPTR, FCNT, RROW, RSRC, RVAL);
    wedges_kernel<<<2 * EB, 256, 0, stream>>>(IDX, VALS, RROW, RSRC, RVAL, WFWD, WREV);
    // 8. t1 = x1 @ W1
    {
        dim3 g(D_H / BN, NN_NODES / BM);
        gemm_nn_kernel<<<g, 256, 0, stream>>>(X1, W1, T1, NN_NODES, D_H, D_IN, nullptr, 0);
    }
    // 9. h1 = relu(prop(t1) + b1)
    prop_gather<<<NN_NODES, D_H, 0, stream>>>(H1, T1, DINV, EPTR, ESRT, b1, D_H, 1);
    // 10. z1 = elu(prop(h1@W2) + b2)
    {
        dim3 g(D_H / BN, NN_NODES / BM);
        gemm_nn_kernel<<<g, 256, 0, stream>>>(H1, W2, T2, NN_NODES, D_H, D_H, nullptr, 0);
    }
    prop_gather<<<NN_NODES, D_H, 0, stream>>>(Z1, T2, DINV, EPTR, ESRT, b2, D_H, 2);
    // 11. g1 = relu(W @ t1 + b1)   [sparse]
    spmm_kernel<<<NN_NODES, 256, 0, stream>>>(G1, T1, IDX, WFWD, RPTR, RSRC, WREV, b1, 1);
    // 12. g2 = g1 @ W2 (into T2)
    {
        dim3 g(D_H / BN, NN_NODES / BM);
        gemm_nn_kernel<<<g, 256, 0, stream>>>(G1, W2, T2, NN_NODES, D_H, D_H, nullptr, 0);
    }
    // 13. z2 = elu(W @ g2 + b2)   [sparse]
    spmm_kernel<<<NN_NODES, 256, 0, stream>>>(Z2, T2, IDX, WFWD, RPTR, RSRC, WREV, b2, 2);
    // 14. normalize z1, z2 -> bf16 (single launch), then diag dots
    rownorm2_kernel<<<2 * NN_NODES, 256, 0, stream>>>(Z1, Z1bf, Z2, Z2bf);
    diag_kernel<<<NN_NODES / 4, 256, 0, stream>>>(Z1bf, Z2bf, DIAG);
    // 15. zrow only: row-sums of exp(5 * z1n@z2n^T) — no 67 MB S materialization
    {
        dim3 g(NN_NODES / 128, NN_NODES / 128);
        gemm_nt_mfma<<<g, 256, 0, stream>>>(Z1bf, Z2bf, nullptr, ZROW);
    }
    // 16. pf / pb (fused fwd+rev, S entries recomputed from bf16 rows in L2)
    {
        int blocks = (2 * NEDGE * 16 + 255) / 256;
        pfpb_edges<<<blocks, 256, 0, stream>>>(Z1bf, Z2bf, IDX, WFWD, RROW, RSRC, WREV, ZROW, PF, PB);
    }
    // 17. loss
    loss_kernel<<<1, 256, 0, stream>>>(DIAG, ZROW, PF, PB, (float*)d_out);
}

// Round 4
// 421.054 us; speedup vs baseline: 1.0667x; 1.0667x over previous
//
#include <hip/hip_runtime.h>
#include <math.h>

#define NN_NODES 4096
#define D_IN 128
#define D_H 256
#define KTOP 17
#define NEDGE (NN_NODES * KTOP)
#define INV_TEMP 5.0f
#define EPSV 1e-8f
#define CCAP 1024

typedef __bf16 bf16x8 __attribute__((ext_vector_type(8)));
typedef float f32x4 __attribute__((ext_vector_type(4)));

// ---------------- helpers ----------------
__device__ __forceinline__ float block_reduce_sum(float v, float* sb) {
#pragma unroll
    for (int o = 32; o > 0; o >>= 1) v += __shfl_down(v, o, 64);
    int wid = threadIdx.x >> 6;
    __syncthreads();
    if ((threadIdx.x & 63) == 0) sb[wid] = v;
    __syncthreads();
    return sb[0] + sb[1] + sb[2] + sb[3];
}

// fp32 -> bf16 (RNE)
__device__ __forceinline__ unsigned short f2bf(float x) {
    unsigned u = __float_as_uint(x);
    unsigned r = u + 0x7fff + ((u >> 16) & 1);
    return (unsigned short)(r >> 16);
}

// bf16 pair unpack (stored as 2x u16 in a u32)
__device__ __forceinline__ float bflo(unsigned x) { return __uint_as_float(x << 16); }
__device__ __forceinline__ float bfhi(unsigned x) { return __uint_as_float(x & 0xffff0000u); }

__device__ __forceinline__ float dot8bf(uint4 a, uint4 b) {
    float s = bflo(a.x) * bflo(b.x) + bfhi(a.x) * bfhi(b.x);
    s += bflo(a.y) * bflo(b.y) + bfhi(a.y) * bfhi(b.y);
    s += bflo(a.z) * bflo(b.z) + bfhi(a.z) * bfhi(b.z);
    s += bflo(a.w) * bflo(b.w) + bfhi(a.w) * bfhi(b.w);
    return s;
}

// async global -> LDS, 16 bytes per lane. lds dest must be wave-uniform base;
// HW deposits at base + lane*16. global address is per-lane.
__device__ __forceinline__ void gl_lds16(const void* g, void* l) {
    __builtin_amdgcn_global_load_lds(
        (const __attribute__((address_space(1))) void*)(g),
        (__attribute__((address_space(3))) void*)(l), 16, 0, 0);
}

// ---------------- elementwise / setup ----------------
__global__ __launch_bounds__(256) void zero_f(float* p, int n) {
    int i = blockIdx.x * 256 + threadIdx.x;
    if (i < n) p[i] = 0.f;
}

__global__ __launch_bounds__(256) void zero_i(int* p, int n) {
    int i = blockIdx.x * 256 + threadIdx.x;
    if (i < n) p[i] = 0;
}

__global__ __launch_bounds__(256) void x1_kernel(const float* __restrict__ x,
                                                 const float* __restrict__ p_feat,
                                                 const float* __restrict__ p_shared,
                                                 float* __restrict__ x1) {
    int i = blockIdx.x * 256 + threadIdx.x;
    if (i >= NN_NODES * D_IN) return;
    int c = i & (D_IN - 1);
    float v = x[i] * p_feat[c];
    v = fmaxf(v, 0.0f) * p_shared[c];
    x1[i] = v;
}

// dinv[i] = rsqrt(1 + indegree[i])
__global__ __launch_bounds__(256) void to_dinv(const int* __restrict__ cnt, float* __restrict__ dinv) {
    int i = blockIdx.x * 256 + threadIdx.x;
    if (i < NN_NODES) dinv[i] = rsqrtf(1.0f + (float)cnt[i]);
}

// ---------------- input-graph CSR (keyed by dst) ----------------
__global__ __launch_bounds__(256) void ecount_kernel(const int* __restrict__ dst, int* __restrict__ cnt, int E) {
    int e = blockIdx.x * 256 + threadIdx.x;
    if (e < E) atomicAdd(&cnt[dst[e]], 1);
}

__global__ __launch_bounds__(256) void efill_kernel(const int* __restrict__ src, const int* __restrict__ dst,
                                                    const int* __restrict__ ptr, int* __restrict__ cnt,
                                                    int* __restrict__ esrt, int E) {
    int e = blockIdx.x * 256 + threadIdx.x;
    if (e >= E) return;
    int d = dst[e];
    int p = ptr[d] + atomicAdd(&cnt[d], 1);
    esrt[p] = src[e];
}

// out[n][c] = act( dinv[n]^2*h[n][c] + sum_{edges s->n} dinv[s]*dinv[n]*h[s][c] + bias[c] )
__global__ void prop_gather(float* __restrict__ out, const float* __restrict__ h,
                            const float* __restrict__ dinv, const int* __restrict__ eptr,
                            const int* __restrict__ esrt, const float* __restrict__ bias,
                            int C, int act) {
    int n = blockIdx.x, t = threadIdx.x;
    float dn = dinv[n];
    float acc = dn * dn * h[(size_t)n * C + t];
    int p1 = eptr[n + 1];
    for (int p = eptr[n]; p < p1; ++p) {
        int s = esrt[p];
        acc += dinv[s] * dn * h[(size_t)s * C + t];
    }
    if (bias) acc += bias[t];
    if (act == 1) acc = fmaxf(acc, 0.f);
    else if (act == 2) acc = acc > 0.f ? acc : expm1f(acc);
    out[(size_t)n * C + t] = acc;
}

// h = concat(x1, agg)*p_balance; hn = h/(||h||+eps) -> bf16
__global__ __launch_bounds__(256) void h_hn_kernel(const float* __restrict__ x1,
                                                   const float* __restrict__ agg,
                                                   const float* __restrict__ p_balance,
                                                   unsigned short* __restrict__ hn_bf) {
    __shared__ float sb[4];
    int n = blockIdx.x, t = threadIdx.x;
    float v;
    if (t < D_IN) v = x1[(size_t)n * D_IN + t] * p_balance[t];
    else v = agg[(size_t)n * D_IN + (t - D_IN)] * p_balance[t];
    float ss = block_reduce_sum(v * v, sb);
    float inv = 1.0f / (sqrtf(ss) + EPSV);
    hn_bf[(size_t)n * D_H + t] = f2bf(v * inv);
}

// row normalize two Z buffers -> bf16 in one launch (grid 2*NN_NODES)
__global__ __launch_bounds__(256) void rownorm2_kernel(const float* __restrict__ Z1,
                                                       unsigned short* __restrict__ z1bf,
                                                       const float* __restrict__ Z2,
                                                       unsigned short* __restrict__ z2bf) {
    __shared__ float sb[4];
    int b = blockIdx.x, t = threadIdx.x;
    const float* Z = (b < NN_NODES) ? Z1 : Z2;
    unsigned short* zbf = (b < NN_NODES) ? z1bf : z2bf;
    int n = (b < NN_NODES) ? b : b - NN_NODES;
    float v = Z[(size_t)n * D_H + t];
    float ss = block_reduce_sum(v * v, sb);
    float inv = 1.0f / (sqrtf(ss) + EPSV);
    zbf[(size_t)n * D_H + t] = f2bf(v * inv);
}

// diag[i] = dot(z1n[i], z2n[i])  (one wave per row)
__global__ __launch_bounds__(256) void diag_kernel(const unsigned short* __restrict__ z1,
                                                   const unsigned short* __restrict__ z2,
                                                   float* __restrict__ diag) {
    int row = blockIdx.x * 4 + (threadIdx.x >> 6);
    int lane = threadIdx.x & 63;
    uint2 ua = *(const uint2*)&z1[(size_t)row * D_H + lane * 4];
    uint2 ub = *(const uint2*)&z2[(size_t)row * D_H + lane * 4];
    float s = bflo(ua.x) * bflo(ub.x) + bfhi(ua.x) * bfhi(ub.x) +
              bflo(ua.y) * bflo(ub.y) + bfhi(ua.y) * bfhi(ub.y);
#pragma unroll
    for (int o = 32; o > 0; o >>= 1) s += __shfl_down(s, o, 64);
    if (lane == 0) diag[row] = s;
}

// ---------------- fp32 GEMM (small NN cases) ----------------
#define BM 64
#define BN 64
#define BK 16

__global__ __launch_bounds__(256) void gemm_nn_kernel(const float* __restrict__ A,
                                                      const float* __restrict__ B,
                                                      float* __restrict__ C, int M, int Nn,
                                                      int Kk, const float* __restrict__ bias,
                                                      int ep) {
    __shared__ float As[BK][BM + 4];
    __shared__ float Bs[BK][BN + 4];
    const int tid = threadIdx.x;
    const int tx = tid & 15, ty = tid >> 4;
    const int m0 = blockIdx.y * BM, n0 = blockIdx.x * BN;
    const int arow = tid >> 2, acol = (tid & 3) << 2;
    const int brow = tid >> 4, bcol = (tid & 15) << 2;
    float acc[4][4] = {{0.f}};

    for (int k0 = 0; k0 < Kk; k0 += BK) {
        float4 av = *(const float4*)&A[(size_t)(m0 + arow) * Kk + k0 + acol];
        float4 bv = *(const float4*)&B[(size_t)(k0 + brow) * Nn + n0 + bcol];
        As[acol + 0][arow] = av.x;
        As[acol + 1][arow] = av.y;
        As[acol + 2][arow] = av.z;
        As[acol + 3][arow] = av.w;
        *(float4*)&Bs[brow][bcol] = bv;
        __syncthreads();
#pragma unroll
        for (int k = 0; k < BK; ++k) {
            float4 a = *(const float4*)&As[k][ty << 2];
            float4 b = *(const float4*)&Bs[k][tx << 2];
            acc[0][0] += a.x * b.x; acc[0][1] += a.x * b.y; acc[0][2] += a.x * b.z; acc[0][3] += a.x * b.w;
            acc[1][0] += a.y * b.x; acc[1][1] += a.y * b.y; acc[1][2] += a.y * b.z; acc[1][3] += a.y * b.w;
            acc[2][0] += a.z * b.x; acc[2][1] += a.z * b.y; acc[2][2] += a.z * b.z; acc[2][3] += a.z * b.w;
            acc[3][0] += a.w * b.x; acc[3][1] += a.w * b.y; acc[3][2] += a.w * b.z; acc[3][3] += a.w * b.w;
        }
        __syncthreads();
    }
    float bb[4] = {0.f, 0.f, 0.f, 0.f};
    if (ep) {
#pragma unroll
        for (int j = 0; j < 4; ++j) bb[j] = bias[n0 + (tx << 2) + j];
    }
#pragma unroll
    for (int i = 0; i < 4; ++i) {
        int m = m0 + (ty << 2) + i;
        float r[4];
#pragma unroll
        for (int j = 0; j < 4; ++j) {
            float v = acc[i][j] + bb[j];
            if (ep == 1) v = fmaxf(v, 0.0f);
            else if (ep == 2) v = v > 0.0f ? v : expm1f(v);
            r[j] = v;
        }
        *(float4*)&C[(size_t)m * Nn + n0 + (tx << 2)] = *(float4*)r;
    }
}

// ---------------- MFMA NT GEMM: C[4096,4096] = X @ Y^T, K=256, single bf16 ----------------
// 256x256 tile per block (grid 16x16 = 256 blocks, 4x fewer than 128^2), 8 waves
// (2 Mwaves x 4 Nwaves), BK=64, double-buffered 128 KB LDS, 2-phase pipeline:
// stage(t+1) issued before compute(t), one vmcnt(0)+barrier per step.
// XOR bank swizzle on 128 B step-rows: colb ^= (row&7)<<4, applied to the
// GLOBAL source during gl_lds16 staging and identically on ds_read.
// C may be nullptr (zrow-only pass).
__global__ __launch_bounds__(512) void gemm_nt_mfma(const unsigned short* __restrict__ Abf,
                                                    const unsigned short* __restrict__ Bbf,
                                                    float* __restrict__ C,
                                                    float* __restrict__ zrow) {
    __shared__ char lds[131072];  // 2 halves x (A 32KB + B 32KB)
    const int tid = threadIdx.x;
    const int w = tid >> 6, lane = tid & 63;
    const int wr = w >> 2, wc = w & 3;            // wave tile: rows wr*128, cols wc*64
    const int m0 = blockIdx.y * 256, n0 = blockIdx.x * 256;
    const int lrow = lane & 15, lquad = lane >> 4;

    f32x4 acc[8][4];
#pragma unroll
    for (int i = 0; i < 8; ++i)
#pragma unroll
        for (int j = 0; j < 4; ++j) acc[i][j] = (f32x4)(0.f);

    const char* Ag = (const char*)Abf + (size_t)m0 * 512;  // 256-row panel, 512 B rows
    const char* Bg = (const char*)Bbf + (size_t)n0 * 512;

    // stage one BK=64 step (A 256x64 + B 256x64 bf16 = 64 KB) into half-buffer.
    // LDS step layout: [256 rows][128 B], swizzled; linear gl_lds16 dest.
    const int ssub = ((lane & 7) << 4) ^ (((lane >> 3) & 7) << 4);  // swizzled col byte
    auto stage = [&](int half, int k0) {
        char* Abuf = lds + half * 65536;
        char* Bbuf = Abuf + 32768;
#pragma unroll
        for (int ti = 0; ti < 4; ++ti) {
            int chunk = ti * 8 + w;                 // 0..31, wave-uniform
            int row = chunk * 8 + (lane >> 3);      // 0..255
            size_t gb = (size_t)row * 512 + (size_t)k0 * 2 + ssub;
            gl_lds16(Ag + gb, Abuf + chunk * 1024);
            gl_lds16(Bg + gb, Bbuf + chunk * 1024);
        }
    };

    auto compute = [&](int half) {
        const char* Abuf = lds + half * 65536;
        const char* Bbuf = Abuf + 32768;
#pragma unroll
        for (int ksub = 0; ksub < 2; ++ksub) {
            int co = (ksub * 64 + lquad * 16) ^ ((lrow & 7) << 4);
            bf16x8 a[8], b[4];
#pragma unroll
            for (int fi = 0; fi < 8; ++fi) {
                int row = wr * 128 + fi * 16 + lrow;
                a[fi] = __builtin_bit_cast(bf16x8, *(const uint4*)(Abuf + row * 128 + co));
            }
#pragma unroll
            for (int fj = 0; fj < 4; ++fj) {
                int row = wc * 64 + fj * 16 + lrow;
                b[fj] = __builtin_bit_cast(bf16x8, *(const uint4*)(Bbuf + row * 128 + co));
            }
#pragma unroll
            for (int fi = 0; fi < 8; ++fi)
#pragma unroll
                for (int fj = 0; fj < 4; ++fj)
                    acc[fi][fj] = __builtin_amdgcn_mfma_f32_16x16x32_bf16(a[fi], b[fj], acc[fi][fj], 0, 0, 0);
        }
    };

    stage(0, 0);
    __syncthreads();
    stage(1, 64);  compute(0); __syncthreads();
    stage(0, 128); compute(1); __syncthreads();
    stage(1, 192); compute(0); __syncthreads();
    compute(1);

    const int rq = (lane >> 4) * 4;
    if (C) {
        const int c0 = lane & 3;
        const int cg = ((lane & 15) >> 2) << 2;  // 4-col group base within 16-col tile
#pragma unroll
        for (int fi = 0; fi < 8; ++fi) {
            int row = m0 + wr * 128 + fi * 16 + rq + c0;
#pragma unroll
            for (int fj = 0; fj < 4; ++fj) {
                float a0 = acc[fi][fj][0], a1 = acc[fi][fj][1], a2 = acc[fi][fj][2], a3 = acc[fi][fj][3];
                // 4x4 transpose across (lane-quad, reg): stage 1 (xor 1)
                float x0 = __shfl_xor(a1, 1, 64), x1 = __shfl_xor(a0, 1, 64);
                float x2 = __shfl_xor(a3, 1, 64), x3 = __shfl_xor(a2, 1, 64);
                bool odd = (c0 & 1) != 0;
                float t0 = odd ? x0 : a0;
                float t1 = odd ? a1 : x1;
                float t2 = odd ? x2 : a2;
                float t3 = odd ? a3 : x3;
                // stage 2 (xor 2)
                float y0 = __shfl_xor(t2, 2, 64), y2 = __shfl_xor(t0, 2, 64);
                float y1 = __shfl_xor(t3, 2, 64), y3 = __shfl_xor(t1, 2, 64);
                bool hi = (c0 & 2) != 0;
                f32x4 o;
                o[0] = hi ? y0 : t0;
                o[1] = hi ? y1 : t1;
                o[2] = hi ? t2 : y2;
                o[3] = hi ? t3 : y3;
                int cb = n0 + wc * 64 + fj * 16 + cg;
                *(f32x4*)&C[(size_t)row * NN_NODES + cb] = o;
            }
        }
    }
    if (zrow) {
#pragma unroll
        for (int fi = 0; fi < 8; ++fi) {
            int rb = m0 + wr * 128 + fi * 16 + rq;
#pragma unroll
            for (int r = 0; r < 4; ++r) {
                float s = 0.f;
#pragma unroll
                for (int fj = 0; fj < 4; ++fj) s += __expf(INV_TEMP * acc[fi][fj][r]);
#pragma unroll
                for (int o = 1; o < 16; o <<= 1) s += __shfl_xor(s, o, 64);
                if ((lane & 15) == 0) atomicAdd(&zrow[rb + r], s);
            }
        }
    }
}

// ---------------- top-k: threshold prefilter + rank-based selection ----------------
__global__ __launch_bounds__(256) void topk_kernel(const float* __restrict__ S,
                                                   float* __restrict__ vals,
                                                   int* __restrict__ idxo) {
    __shared__ float sm[256];
    __shared__ int ccnt;
    __shared__ float cv[CCAP];
    __shared__ int ci[CCAP];
    __shared__ float wvs[8];
    __shared__ int wis[8];
    const int i = blockIdx.x, t = threadIdx.x;
    const int lane = t & 63, wid = t >> 6;
    const float* row = &S[(size_t)i * NN_NODES];
    float v[16];
    int id[16];
#pragma unroll
    for (int u = 0; u < 4; ++u) {
        int base = u * 1024 + t * 4;
        float4 f = *(const float4*)&row[base];
        v[u * 4 + 0] = f.x; id[u * 4 + 0] = base + 0;
        v[u * 4 + 1] = f.y; id[u * 4 + 1] = base + 1;
        v[u * 4 + 2] = f.z; id[u * 4 + 2] = base + 2;
        v[u * 4 + 3] = f.w; id[u * 4 + 3] = base + 3;
    }
    float m = v[0];
#pragma unroll
    for (int u = 1; u < 16; ++u) m = fmaxf(m, v[u]);
    sm[t] = m;
    if (t == 0) ccnt = 0;
    __syncthreads();

    // every wave: T = 17th-largest of 64 group maxima (rank via shfl loop)
    float g = fmaxf(fmaxf(sm[lane * 4 + 0], sm[lane * 4 + 1]),
                    fmaxf(sm[lane * 4 + 2], sm[lane * 4 + 3]));
    int rank = 0;
#pragma unroll
    for (int o = 1; o < 64; ++o) {
        float ov = __shfl_xor(g, o, 64);
        int ol = lane ^ o;
        if (ov > g || (ov == g && ol < lane)) rank++;
    }
    unsigned long long ball = __ballot(rank == 16);
    int tl = __ffsll((long long)ball) - 1;
    const float T = __shfl(g, tl, 64);

    // emit candidates >= T
#pragma unroll
    for (int u = 0; u < 16; ++u) {
        if (v[u] >= T) {
            int p = atomicAdd(&ccnt, 1);
            if (p < CCAP) { cv[p] = v[u]; ci[p] = id[u]; }
        }
    }
    __syncthreads();
    const int cnt = ccnt;

    if (cnt <= CCAP) {
        for (int p = t; p < cnt; p += 256) {
            float mv = cv[p];
            int mi = ci[p];
            int r = 0;
            for (int q = 0; q < cnt; ++q) {
                float qv = cv[q];
                int qi = ci[q];
                if (qv > mv || (qv == mv && qi < mi)) r++;
            }
            if (r < KTOP) {
                vals[i * KTOP + r] = isnan(mv) ? 0.f : mv;
                idxo[i * KTOP + r] = mi;
            }
        }
    } else {
        float bv = v[0];
        int bi = id[0];
#pragma unroll
        for (int u = 1; u < 16; ++u)
            if (v[u] > bv || (v[u] == bv && id[u] < bi)) { bv = v[u]; bi = id[u]; }
        for (int k = 0; k < KTOP; ++k) {
            float mv = bv;
            int mi = bi;
#pragma unroll
            for (int o = 1; o < 64; o <<= 1) {
                float ov = __shfl_xor(mv, o, 64);
                int oi = __shfl_xor(mi, o, 64);
                if (ov > mv || (ov == mv && oi < mi)) { mv = ov; mi = oi; }
            }
            int slot = ((k & 1) << 2) + wid;
            if (lane == 0) { wvs[slot] = mv; wis[slot] = mi; }
            __syncthreads();
            int b0 = (k & 1) << 2;
            mv = wvs[b0]; mi = wis[b0];
#pragma unroll
            for (int ww = 1; ww < 4; ++ww) {
                float ov = wvs[b0 + ww];
                int oi = wis[b0 + ww];
                if (ov > mv || (ov == mv && oi < mi)) { mv = ov; mi = oi; }
            }
            if (t == 0) {
                vals[i * KTOP + k] = isnan(mv) ? 0.f : mv;
                idxo[i * KTOP + k] = mi;
            }
            if (bi == mi) {
#pragma unroll
                for (int u = 0; u < 16; ++u)
                    if (id[u] == mi) v[u] = -INFINITY;
                bv = v[0]; bi = id[0];
#pragma unroll
                for (int u = 1; u < 16; ++u)
                    if (v[u] > bv || (v[u] == bv && id[u] < bi)) { bv = v[u]; bi = id[u]; }
            }
        }
    }
}

// ---------------- sparse W construction ----------------
__global__ __launch_bounds__(256) void count_indeg(const int* __restrict__ idx, int* __restrict__ cnt) {
    int e = blockIdx.x * 256 + threadIdx.x;
    if (e < NEDGE) atomicAdd(&cnt[idx[e]], 1);
}

__global__ __launch_bounds__(256) void scan_kernel(int* __restrict__ cnt, int* __restrict__ ptr) {
    __shared__ int tmp[256];
    int t = threadIdx.x;
    int base = t * 16;
    int local[16]; int s = 0;
#pragma unroll
    for (int u = 0; u < 16; ++u) { local[u] = s; s += cnt[base + u]; }
#pragma unroll
    for (int u = 0; u < 16; ++u) cnt[base + u] = 0;
    tmp[t] = s;
    __syncthreads();
    for (int off = 1; off < 256; off <<= 1) {
        int v = (t >= off) ? tmp[t - off] : 0;
        __syncthreads();
        tmp[t] += v;
        __syncthreads();
    }
    int prefix = (t > 0) ? tmp[t - 1] : 0;
#pragma unroll
    for (int u = 0; u < 16; ++u) ptr[base + u] = prefix + local[u];
    if (t == 255) ptr[NN_NODES] = prefix + s;
}

__global__ __launch_bounds__(256) void fill_rev(const int* __restrict__ idx, const float* __restrict__ vals,
                                                const int* __restrict__ ptr, int* __restrict__ fcnt,
                                                int* __restrict__ rrow, int* __restrict__ rsrc,
                                                float* __restrict__ rval) {
    int e = blockIdx.x * 256 + threadIdx.x;
    if (e >= NEDGE) return;
    int i = e / KTOP;
    int j = idx[e];
    int p = ptr[j] + atomicAdd(&fcnt[j], 1);
    rrow[p] = j; rsrc[p] = i; rval[p] = vals[e];
}

// fused fwd+rev edge weights (grid covers 2*NEDGE)
__global__ __launch_bounds__(256) void wedges_kernel(const int* __restrict__ idx, const float* __restrict__ vals,
                                                     const int* __restrict__ rrow, const int* __restrict__ rsrc,
                                                     const float* __restrict__ rval,
                                                     float* __restrict__ wfwd, float* __restrict__ wrev) {
    int e = blockIdx.x * 256 + threadIdx.x;
    if (e < NEDGE) {
        int i = e / KTOP;
        int j = idx[e];
        float a = vals[e];
        float c = 1.0f;
        const int* lj = &idx[j * KTOP];
#pragma unroll
        for (int k = 0; k < KTOP; ++k)
            if (lj[k] == i) { a += vals[j * KTOP + k]; c = 2.0f; }
        float w = a / c;
        wfwd[e] = w > 0.f ? w : 0.f;
    } else if (e < 2 * NEDGE) {
        int e2 = e - NEDGE;
        int i = rrow[e2], s = rsrc[e2];
        const int* li = &idx[i * KTOP];
        bool dup = false;
#pragma unroll
        for (int k = 0; k < KTOP; ++k)
            if (li[k] == s) dup = true;
        wrev[e2] = dup ? 0.f : fmaxf(rval[e2], 0.f);
    }
}

// out[i,:] = act(sum_j W[i,j]*X[j,:] + bias)
__global__ __launch_bounds__(256) void spmm_kernel(float* __restrict__ out, const float* __restrict__ X,
                                                   const int* __restrict__ idx, const float* __restrict__ wfwd,
                                                   const int* __restrict__ ptr, const int* __restrict__ rsrc,
                                                   const float* __restrict__ wrev,
                                                   const float* __restrict__ bias, int act) {
    int i = blockIdx.x, c = threadIdx.x;
    float acc = 0.f;
#pragma unroll
    for (int k = 0; k < KTOP; ++k) {
        int j = idx[i * KTOP + k];
        float w = wfwd[i * KTOP + k];
        acc += w * X[(size_t)j * D_H + c];
    }
    int p1 = ptr[i + 1];
    for (int p = ptr[i]; p < p1; ++p) {
        float w = wrev[p];
        if (w != 0.f) acc += w * X[(size_t)rsrc[p] * D_H + c];
    }
    acc += bias[c];
    if (act == 1) acc = fmaxf(acc, 0.f);
    else acc = acc > 0.f ? acc : expm1f(acc);
    out[(size_t)i * D_H + c] = acc;
}

// fused pf/pb over fwd+rev lists; S entries recomputed as bf16 dots (16 lanes/edge)
__global__ __launch_bounds__(256) void pfpb_edges(const unsigned short* __restrict__ z1,
                                                  const unsigned short* __restrict__ z2,
                                                  const int* __restrict__ idx,
                                                  const float* __restrict__ wfwd,
                                                  const int* __restrict__ rrow,
                                                  const int* __restrict__ rsrc,
                                                  const float* __restrict__ wrev,
                                                  const float* __restrict__ zrow,
                                                  float* __restrict__ pf, float* __restrict__ pb) {
    int g = (blockIdx.x * 256 + threadIdx.x) >> 4;  // edge id
    int l = threadIdx.x & 15;
    if (g >= 2 * NEDGE) return;
    int i, j;
    float wv;
    if (g < NEDGE) { i = g / KTOP; j = idx[g]; wv = wfwd[g]; }
    else { int e2 = g - NEDGE; i = rrow[e2]; j = rsrc[e2]; wv = wrev[e2]; }
    if (wv == 0.f) return;
    // lane l covers dims [16*l, 16*l+16)
    const uint4* a1 = (const uint4*)&z1[(size_t)i * D_H + l * 16];
    const uint4* b1 = (const uint4*)&z2[(size_t)j * D_H + l * 16];
    const uint4* a2 = (const uint4*)&z1[(size_t)j * D_H + l * 16];
    const uint4* b2 = (const uint4*)&z2[(size_t)i * D_H + l * 16];
    float s1 = dot8bf(a1[0], b1[0]) + dot8bf(a1[1], b1[1]);  // S[i][j]
    float s2 = dot8bf(a2[0], b2[0]) + dot8bf(a2[1], b2[1]);  // S[j][i]
#pragma unroll
    for (int o = 8; o > 0; o >>= 1) {
        s1 += __shfl_xor(s1, o, 64);
        s2 += __shfl_xor(s2, o, 64);
    }
    if (l == 0) {
        float pfv = expf(s1 * INV_TEMP) / zrow[i] * wv;
        float pbv = expf(s2 * INV_TEMP) / zrow[j] * wv;
        atomicAdd(&pf[i], pfv);
        atomicAdd(&pb[i], pbv);
    }
}

__global__ __launch_bounds__(256) void loss_kernel(const float* __restrict__ diag,
                                                   const float* __restrict__ zrow,
                                                   const float* __restrict__ pf,
                                                   const float* __restrict__ pb,
                                                   float* __restrict__ out) {
    __shared__ float sb[4];
    int t = threadIdx.x;
    float s = 0.f;
    for (int i = t; i < NN_NODES; i += 256) {
        float p = expf(INV_TEMP * diag[i]) / zrow[i];
        s += -logf(fmaxf(p, EPSV));
        s += 0.5f * (-logf(fmaxf(pf[i], EPSV)) - logf(fmaxf(pb[i], EPSV)));
    }
    float tot = block_reduce_sum(s, sb);
    if (t == 0) out[0] = tot / (float)NN_NODES;
}

// ---------------- launch ----------------
extern "C" void kernel_launch(void* const* d_in, const int* in_sizes, int n_in,
                              void* d_out, int out_size, void* d_ws, size_t ws_size,
                              hipStream_t stream) {
    (void)n_in; (void)out_size; (void)ws_size;
    const float* x = (const float*)d_in[0];
    const int* esrc = (const int*)d_in[1];
    const int* edst = (const int*)d_in[2];
    const float* p_feat = (const float*)d_in[3];
    const float* p_shared = (const float*)d_in[4];
    const float* p_balance = (const float*)d_in[5];
    const float* W1 = (const float*)d_in[6];
    const float* b1 = (const float*)d_in[7];
    const float* W2 = (const float*)d_in[8];
    const float* b2 = (const float*)d_in[9];
    const int E = in_sizes[1];

    float* ws = (float*)d_ws;
    size_t off = 0;
    float* SIM = ws + off; off += (size_t)NN_NODES * NN_NODES;
    float* X1  = ws + off; off += (size_t)NN_NODES * D_IN;
    float* AGG = ws + off; off += (size_t)NN_NODES * D_IN;
    float* T1  = ws + off; off += (size_t)NN_NODES * D_H;
    float* H1  = ws + off; off += (size_t)NN_NODES * D_H;
    float* T2  = ws + off; off += (size_t)NN_NODES * D_H;
    float* Z1  = ws + off; off += (size_t)NN_NODES * D_H;
    float* G1  = ws + off; off += (size_t)NN_NODES * D_H;
    float* Z2  = ws + off; off += (size_t)NN_NODES * D_H;
    float* DINV = ws + off; off += NN_NODES;
    float* VALS = ws + off; off += (size_t)NEDGE;
    int*   IDX  = (int*)(ws + off); off += (size_t)NEDGE;
    float* WFWD = ws + off; off += (size_t)NEDGE;
    int*   RPTR = (int*)(ws + off); off += NN_NODES + 1;
    int*   FCNT = (int*)(ws + off); off += NN_NODES;
    int*   RROW = (int*)(ws + off); off += (size_t)NEDGE;
    int*   RSRC = (int*)(ws + off); off += (size_t)NEDGE;
    float* RVAL = ws + off; off += (size_t)NEDGE;
    float* WREV = ws + off; off += (size_t)NEDGE;
    float* ZROW = ws + off; off += NN_NODES;   // ZROW,PF,PB contiguous (zeroed together)
    float* PF = ws + off; off += NN_NODES;
    float* PB = ws + off; off += NN_NODES;
    float* DIAG = ws + off; off += NN_NODES;
    unsigned short* HNbf = (unsigned short*)(ws + off); off += (size_t)NN_NODES * D_H / 2;
    unsigned short* Z1bf = (unsigned short*)(ws + off); off += (size_t)NN_NODES * D_H / 2;
    unsigned short* Z2bf = (unsigned short*)(ws + off); off += (size_t)NN_NODES * D_H / 2;
    int* ECNT = (int*)(ws + off); off += NN_NODES;
    int* EPTR = (int*)(ws + off); off += NN_NODES + 1;
    int* ESRT = (int*)(ws + off); off += (size_t)E;

    const int EB = (NEDGE + 255) / 256;
    const int NB = (NN_NODES + 255) / 256;
    const int EBi = (E + 255) / 256;

    // 1. x1
    x1_kernel<<<(NN_NODES * D_IN + 255) / 256, 256, 0, stream>>>(x, p_feat, p_shared, X1);
    // 2. input-graph CSR + dinv (deg = 1 + indegree)
    zero_i<<<NB, 256, 0, stream>>>(ECNT, NN_NODES);
    ecount_kernel<<<EBi, 256, 0, stream>>>(edst, ECNT, E);
    to_dinv<<<NB, 256, 0, stream>>>(ECNT, DINV);
    scan_kernel<<<1, 256, 0, stream>>>(ECNT, EPTR);  // zeroes ECNT for efill
    efill_kernel<<<EBi, 256, 0, stream>>>(esrc, edst, EPTR, ECNT, ESRT, E);
    // zero ZROW/PF/PB (contiguous)
    zero_f<<<(3 * NN_NODES + 255) / 256, 256, 0, stream>>>(ZROW, 3 * NN_NODES);
    // 3. agg = A_norm @ x1  (gather)
    prop_gather<<<NN_NODES, D_IN, 0, stream>>>(AGG, X1, DINV, EPTR, ESRT, nullptr, D_IN, 0);
    // 4. h, hn (bf16)
    h_hn_kernel<<<NN_NODES, 256, 0, stream>>>(X1, AGG, p_balance, HNbf);
    // 5. sim = hn @ hn^T  (MFMA bf16, 256^2 tile, 2-phase dbuf pipeline)
    {
        dim3 g(NN_NODES / 256, NN_NODES / 256);
        gemm_nt_mfma<<<g, 512, 0, stream>>>(HNbf, HNbf, SIM, nullptr);
    }
    // 6. topk (threshold prefilter + rank selection)
    topk_kernel<<<NN_NODES, 256, 0, stream>>>(SIM, VALS, IDX);
    // 7. sparse W: reverse CSR + fused edge weights
    zero_i<<<NB, 256, 0, stream>>>(FCNT, NN_NODES);
    count_indeg<<<EB, 256, 0, stream>>>(IDX, FCNT);
    scan_kernel<<<1, 256, 0, stream>>>(FCNT, RPTR);  // zeroes FCNT for fill_rev
    fill_rev<<<EB, 256, 0, stream>>>(IDX, VALS, RPTR, FCNT, RROW, RSRC, RVAL);
    wedges_kernel<<<2 * EB, 256, 0, stream>>>(IDX, VALS, RROW, RSRC, RVAL, WFWD, WREV);
    // 8. t1 = x1 @ W1
    {
        dim3 g(D_H / BN, NN_NODES / BM);
        gemm_nn_kernel<<<g, 256, 0, stream>>>(X1, W1, T1, NN_NODES, D_H, D_IN, nullptr, 0);
    }
    // 9. h1 = relu(prop(t1) + b1)
    prop_gather<<<NN_NODES, D_H, 0, stream>>>(H1, T1, DINV, EPTR, ESRT, b1, D_H, 1);
    // 10. z1 = elu(prop(h1@W2) + b2)
    {
        dim3 g(D_H / BN, NN_NODES / BM);
        gemm_nn_kernel<<<g, 256, 0, stream>>>(H1, W2, T2, NN_NODES, D_H, D_H, nullptr, 0);
    }
    prop_gather<<<NN_NODES, D_H, 0, stream>>>(Z1, T2, DINV, EPTR, ESRT, b2, D_H, 2);
    // 11. g1 = relu(W @ t1 + b1)   [sparse]
    spmm_kernel<<<NN_NODES, 256, 0, stream>>>(G1, T1, IDX, WFWD, RPTR, RSRC, WREV, b1, 1);
    // 12. g2 = g1 @ W2 (into T2)
    {
        dim3 g(D_H / BN, NN_NODES / BM);
        gemm_nn_kernel<<<g, 256, 0, stream>>>(G1, W2, T2, NN_NODES, D_H, D_H, nullptr, 0);
    }
    // 13. z2 = elu(W @ g2 + b2)   [sparse]
    spmm_kernel<<<NN_NODES, 256, 0, stream>>>(Z2, T2, IDX, WFWD, RPTR, RSRC, WREV, b2, 2);
    // 14. normalize z1, z2 -> bf16 (single launch), then diag dots
    rownorm2_kernel<<<2 * NN_NODES, 256, 0, stream>>>(Z1, Z1bf, Z2, Z2bf);
    diag_kernel<<<NN_NODES / 4, 256, 0, stream>>>(Z1bf, Z2bf, DIAG);
    // 15. zrow only: row-sums of exp(5 * z1n@z2n^T) — no 67 MB S materialization
    {
        dim3 g(NN_NODES / 256, NN_NODES / 256);
        gemm_nt_mfma<<<g, 512, 0, stream>>>(Z1bf, Z2bf, nullptr, ZROW);
    }
    // 16. pf / pb (fused fwd+rev, S entries recomputed from bf16 rows in L2)
    {
        int blocks = (2 * NEDGE * 16 + 255) / 256;
        pfpb_edges<<<blocks, 256, 0, stream>>>(Z1bf, Z2bf, IDX, WFWD, RROW, RSRC, WREV, ZROW, PF, PB);
    }
    // 17. loss
    loss_kernel<<<1, 256, 0, stream>>>(DIAG, ZROW, PF, PB, (float*)d_out);
}

// Round 5
// 417.996 us; speedup vs baseline: 1.0745x; 1.0073x over previous
//
#include <hip/hip_runtime.h>
#include <math.h>

#define NN_NODES 4096
#define D_IN 128
#define D_H 256
#define KTOP 17
#define NEDGE (NN_NODES * KTOP)
#define INV_TEMP 5.0f
#define EPSV 1e-8f
#define CCAP 1024

typedef __bf16 bf16x8 __attribute__((ext_vector_type(8)));
typedef float f32x4 __attribute__((ext_vector_type(4)));

// ---------------- helpers ----------------
__device__ __forceinline__ float block_reduce_sum(float v, float* sb) {
#pragma unroll
    for (int o = 32; o > 0; o >>= 1) v += __shfl_down(v, o, 64);
    int wid = threadIdx.x >> 6;
    __syncthreads();
    if ((threadIdx.x & 63) == 0) sb[wid] = v;
    __syncthreads();
    return sb[0] + sb[1] + sb[2] + sb[3];
}

// fp32 -> bf16 (RNE)
__device__ __forceinline__ unsigned short f2bf(float x) {
    unsigned u = __float_as_uint(x);
    unsigned r = u + 0x7fff + ((u >> 16) & 1);
    return (unsigned short)(r >> 16);
}

// bf16 pair unpack (stored as 2x u16 in a u32)
__device__ __forceinline__ float bflo(unsigned x) { return __uint_as_float(x << 16); }
__device__ __forceinline__ float bfhi(unsigned x) { return __uint_as_float(x & 0xffff0000u); }

__device__ __forceinline__ float dot8bf(uint4 a, uint4 b) {
    float s = bflo(a.x) * bflo(b.x) + bfhi(a.x) * bfhi(b.x);
    s += bflo(a.y) * bflo(b.y) + bfhi(a.y) * bfhi(b.y);
    s += bflo(a.z) * bflo(b.z) + bfhi(a.z) * bfhi(b.z);
    s += bflo(a.w) * bflo(b.w) + bfhi(a.w) * bfhi(b.w);
    return s;
}

// async global -> LDS, 16 bytes per lane. lds dest must be wave-uniform base;
// HW deposits at base + lane*16. global address is per-lane.
__device__ __forceinline__ void gl_lds16(const void* g, void* l) {
    __builtin_amdgcn_global_load_lds(
        (const __attribute__((address_space(1))) void*)(g),
        (__attribute__((address_space(3))) void*)(l), 16, 0, 0);
}

// raw barrier + scheduler fence (rule #18: hipcc hoists reg-only/DS ops past
// inline-asm waits; sched_barrier(0) pins program order at this point)
#define BARRIER_SB() do { __builtin_amdgcn_s_barrier(); __builtin_amdgcn_sched_barrier(0); } while (0)
#define WAITV(n) do { asm volatile("s_waitcnt vmcnt(" #n ")" ::: "memory"); __builtin_amdgcn_sched_barrier(0); } while (0)

// ---------------- elementwise / setup ----------------
__global__ __launch_bounds__(256) void zero_f(float* p, int n) {
    int i = blockIdx.x * 256 + threadIdx.x;
    if (i < n) p[i] = 0.f;
}

__global__ __launch_bounds__(256) void zero_i(int* p, int n) {
    int i = blockIdx.x * 256 + threadIdx.x;
    if (i < n) p[i] = 0;
}

__global__ __launch_bounds__(256) void x1_kernel(const float* __restrict__ x,
                                                 const float* __restrict__ p_feat,
                                                 const float* __restrict__ p_shared,
                                                 float* __restrict__ x1) {
    int i = blockIdx.x * 256 + threadIdx.x;
    if (i >= NN_NODES * D_IN) return;
    int c = i & (D_IN - 1);
    float v = x[i] * p_feat[c];
    v = fmaxf(v, 0.0f) * p_shared[c];
    x1[i] = v;
}

// dinv[i] = rsqrt(1 + indegree[i])
__global__ __launch_bounds__(256) void to_dinv(const int* __restrict__ cnt, float* __restrict__ dinv) {
    int i = blockIdx.x * 256 + threadIdx.x;
    if (i < NN_NODES) dinv[i] = rsqrtf(1.0f + (float)cnt[i]);
}

// ---------------- input-graph CSR (keyed by dst) ----------------
__global__ __launch_bounds__(256) void ecount_kernel(const int* __restrict__ dst, int* __restrict__ cnt, int E) {
    int e = blockIdx.x * 256 + threadIdx.x;
    if (e < E) atomicAdd(&cnt[dst[e]], 1);
}

__global__ __launch_bounds__(256) void efill_kernel(const int* __restrict__ src, const int* __restrict__ dst,
                                                    const int* __restrict__ ptr, int* __restrict__ cnt,
                                                    int* __restrict__ esrt, int E) {
    int e = blockIdx.x * 256 + threadIdx.x;
    if (e >= E) return;
    int d = dst[e];
    int p = ptr[d] + atomicAdd(&cnt[d], 1);
    esrt[p] = src[e];
}

// out[n][c] = act( dinv[n]^2*h[n][c] + sum_{edges s->n} dinv[s]*dinv[n]*h[s][c] + bias[c] )
__global__ void prop_gather(float* __restrict__ out, const float* __restrict__ h,
                            const float* __restrict__ dinv, const int* __restrict__ eptr,
                            const int* __restrict__ esrt, const float* __restrict__ bias,
                            int C, int act) {
    int n = blockIdx.x, t = threadIdx.x;
    float dn = dinv[n];
    float acc = dn * dn * h[(size_t)n * C + t];
    int p1 = eptr[n + 1];
    for (int p = eptr[n]; p < p1; ++p) {
        int s = esrt[p];
        acc += dinv[s] * dn * h[(size_t)s * C + t];
    }
    if (bias) acc += bias[t];
    if (act == 1) acc = fmaxf(acc, 0.f);
    else if (act == 2) acc = acc > 0.f ? acc : expm1f(acc);
    out[(size_t)n * C + t] = acc;
}

// h = concat(x1, agg)*p_balance; hn = h/(||h||+eps) -> bf16
__global__ __launch_bounds__(256) void h_hn_kernel(const float* __restrict__ x1,
                                                   const float* __restrict__ agg,
                                                   const float* __restrict__ p_balance,
                                                   unsigned short* __restrict__ hn_bf) {
    __shared__ float sb[4];
    int n = blockIdx.x, t = threadIdx.x;
    float v;
    if (t < D_IN) v = x1[(size_t)n * D_IN + t] * p_balance[t];
    else v = agg[(size_t)n * D_IN + (t - D_IN)] * p_balance[t];
    float ss = block_reduce_sum(v * v, sb);
    float inv = 1.0f / (sqrtf(ss) + EPSV);
    hn_bf[(size_t)n * D_H + t] = f2bf(v * inv);
}

// row normalize two Z buffers -> bf16 in one launch (grid 2*NN_NODES)
__global__ __launch_bounds__(256) void rownorm2_kernel(const float* __restrict__ Z1,
                                                       unsigned short* __restrict__ z1bf,
                                                       const float* __restrict__ Z2,
                                                       unsigned short* __restrict__ z2bf) {
    __shared__ float sb[4];
    int b = blockIdx.x, t = threadIdx.x;
    const float* Z = (b < NN_NODES) ? Z1 : Z2;
    unsigned short* zbf = (b < NN_NODES) ? z1bf : z2bf;
    int n = (b < NN_NODES) ? b : b - NN_NODES;
    float v = Z[(size_t)n * D_H + t];
    float ss = block_reduce_sum(v * v, sb);
    float inv = 1.0f / (sqrtf(ss) + EPSV);
    zbf[(size_t)n * D_H + t] = f2bf(v * inv);
}

// diag[i] = dot(z1n[i], z2n[i])  (one wave per row)
__global__ __launch_bounds__(256) void diag_kernel(const unsigned short* __restrict__ z1,
                                                   const unsigned short* __restrict__ z2,
                                                   float* __restrict__ diag) {
    int row = blockIdx.x * 4 + (threadIdx.x >> 6);
    int lane = threadIdx.x & 63;
    uint2 ua = *(const uint2*)&z1[(size_t)row * D_H + lane * 4];
    uint2 ub = *(const uint2*)&z2[(size_t)row * D_H + lane * 4];
    float s = bflo(ua.x) * bflo(ub.x) + bfhi(ua.x) * bfhi(ub.x) +
              bflo(ua.y) * bflo(ub.y) + bfhi(ua.y) * bfhi(ub.y);
#pragma unroll
    for (int o = 32; o > 0; o >>= 1) s += __shfl_down(s, o, 64);
    if (lane == 0) diag[row] = s;
}

// ---------------- fp32 GEMM (small NN cases) ----------------
#define BM 64
#define BN 64
#define BK 16

__global__ __launch_bounds__(256) void gemm_nn_kernel(const float* __restrict__ A,
                                                      const float* __restrict__ B,
                                                      float* __restrict__ C, int M, int Nn,
                                                      int Kk, const float* __restrict__ bias,
                                                      int ep) {
    __shared__ float As[BK][BM + 4];
    __shared__ float Bs[BK][BN + 4];
    const int tid = threadIdx.x;
    const int tx = tid & 15, ty = tid >> 4;
    const int m0 = blockIdx.y * BM, n0 = blockIdx.x * BN;
    const int arow = tid >> 2, acol = (tid & 3) << 2;
    const int brow = tid >> 4, bcol = (tid & 15) << 2;
    float acc[4][4] = {{0.f}};

    for (int k0 = 0; k0 < Kk; k0 += BK) {
        float4 av = *(const float4*)&A[(size_t)(m0 + arow) * Kk + k0 + acol];
        float4 bv = *(const float4*)&B[(size_t)(k0 + brow) * Nn + n0 + bcol];
        As[acol + 0][arow] = av.x;
        As[acol + 1][arow] = av.y;
        As[acol + 2][arow] = av.z;
        As[acol + 3][arow] = av.w;
        *(float4*)&Bs[brow][bcol] = bv;
        __syncthreads();
#pragma unroll
        for (int k = 0; k < BK; ++k) {
            float4 a = *(const float4*)&As[k][ty << 2];
            float4 b = *(const float4*)&Bs[k][tx << 2];
            acc[0][0] += a.x * b.x; acc[0][1] += a.x * b.y; acc[0][2] += a.x * b.z; acc[0][3] += a.x * b.w;
            acc[1][0] += a.y * b.x; acc[1][1] += a.y * b.y; acc[1][2] += a.y * b.z; acc[1][3] += a.y * b.w;
            acc[2][0] += a.z * b.x; acc[2][1] += a.z * b.y; acc[2][2] += a.z * b.z; acc[2][3] += a.z * b.w;
            acc[3][0] += a.w * b.x; acc[3][1] += a.w * b.y; acc[3][2] += a.w * b.z; acc[3][3] += a.w * b.w;
        }
        __syncthreads();
    }
    float bb[4] = {0.f, 0.f, 0.f, 0.f};
    if (ep) {
#pragma unroll
        for (int j = 0; j < 4; ++j) bb[j] = bias[n0 + (tx << 2) + j];
    }
#pragma unroll
    for (int i = 0; i < 4; ++i) {
        int m = m0 + (ty << 2) + i;
        float r[4];
#pragma unroll
        for (int j = 0; j < 4; ++j) {
            float v = acc[i][j] + bb[j];
            if (ep == 1) v = fmaxf(v, 0.0f);
            else if (ep == 2) v = v > 0.0f ? v : expm1f(v);
            r[j] = v;
        }
        *(float4*)&C[(size_t)m * Nn + n0 + (tx << 2)] = *(float4*)r;
    }
}

// ---------------- MFMA NT GEMM: C[4096,4096] = X @ Y^T, K=256, single bf16 ----------------
// 256x256 tile, 8 waves, BK=64, double-buffered 128 KB LDS.
// T4 counted-vmcnt pipeline: raw s_barrier + s_waitcnt vmcnt(8) (= loads/wave/step,
// so the just-issued prefetch stays IN FLIGHT across the barrier); vmcnt(0) only
// before the last step. sched_barrier(0) after every wait/barrier (rule #18).
// MODE 0: write C. MODE 1: zrow-only (row-sums of exp(5*S)).
template <int MODE>
__global__ __launch_bounds__(512) void gemm_nt_mfma(const unsigned short* __restrict__ Abf,
                                                    const unsigned short* __restrict__ Bbf,
                                                    float* __restrict__ C,
                                                    float* __restrict__ zrow) {
    __shared__ char lds[131072];  // 2 halves x (A 32KB + B 32KB)
    const int tid = threadIdx.x;
    const int w = tid >> 6, lane = tid & 63;
    const int wr = w >> 2, wc = w & 3;            // wave tile: rows wr*128, cols wc*64
    const int m0 = blockIdx.y * 256, n0 = blockIdx.x * 256;
    const int lrow = lane & 15, lquad = lane >> 4;

    f32x4 acc[8][4];
#pragma unroll
    for (int i = 0; i < 8; ++i)
#pragma unroll
        for (int j = 0; j < 4; ++j) acc[i][j] = (f32x4)(0.f);

    const char* Ag = (const char*)Abf + (size_t)m0 * 512;  // 256-row panel, 512 B rows
    const char* Bg = (const char*)Bbf + (size_t)n0 * 512;

    // stage one BK=64 step (A 256x64 + B 256x64 bf16 = 64 KB) into half-buffer.
    // LDS step layout: [256 rows][128 B], swizzled; linear gl_lds16 dest.
    // 8 gl_lds16 per wave per step.
    const int ssub = ((lane & 7) << 4) ^ (((lane >> 3) & 7) << 4);  // swizzled col byte
    auto stage = [&](int half, int k0) {
        char* Abuf = lds + half * 65536;
        char* Bbuf = Abuf + 32768;
#pragma unroll
        for (int ti = 0; ti < 4; ++ti) {
            int chunk = ti * 8 + w;                 // 0..31, wave-uniform
            int row = chunk * 8 + (lane >> 3);      // 0..255
            size_t gb = (size_t)row * 512 + (size_t)k0 * 2 + ssub;
            gl_lds16(Ag + gb, Abuf + chunk * 1024);
            gl_lds16(Bg + gb, Bbuf + chunk * 1024);
        }
    };

    auto compute = [&](int half) {
        const char* Abuf = lds + half * 65536;
        const char* Bbuf = Abuf + 32768;
#pragma unroll
        for (int ksub = 0; ksub < 2; ++ksub) {
            int co = (ksub * 64 + lquad * 16) ^ ((lrow & 7) << 4);
            bf16x8 a[8], b[4];
#pragma unroll
            for (int fi = 0; fi < 8; ++fi) {
                int row = wr * 128 + fi * 16 + lrow;
                a[fi] = __builtin_bit_cast(bf16x8, *(const uint4*)(Abuf + row * 128 + co));
            }
#pragma unroll
            for (int fj = 0; fj < 4; ++fj) {
                int row = wc * 64 + fj * 16 + lrow;
                b[fj] = __builtin_bit_cast(bf16x8, *(const uint4*)(Bbuf + row * 128 + co));
            }
#pragma unroll
            for (int fi = 0; fi < 8; ++fi)
#pragma unroll
                for (int fj = 0; fj < 4; ++fj)
                    acc[fi][fj] = __builtin_amdgcn_mfma_f32_16x16x32_bf16(a[fi], b[fj], acc[fi][fj], 0, 0, 0);
        }
    };

    // counted-vmcnt 2-buffer pipeline over 4 K-steps (K=256, BK=64):
    stage(0, 0);        // 8 loads in flight
    stage(1, 64);       // 16 in flight
    WAITV(8); BARRIER_SB();   // buf0 ready (newest 8 = buf1 may remain in flight)
    compute(0);
    BARRIER_SB();             // all waves done reading buf0
    stage(0, 128);            // overwrite buf0; <=16 in flight
    WAITV(8); BARRIER_SB();   // buf1 ready
    compute(1);
    BARRIER_SB();
    stage(1, 192);            // <=16 in flight
    WAITV(8); BARRIER_SB();   // buf0(k=128) ready
    compute(0);
    BARRIER_SB();
    WAITV(0); BARRIER_SB();   // final drain: buf1(k=192) ready
    compute(1);

    const int rq = (lane >> 4) * 4;
    if constexpr (MODE == 0) {
        const int c0 = lane & 3;
        const int cg = ((lane & 15) >> 2) << 2;  // 4-col group base within 16-col tile
#pragma unroll
        for (int fi = 0; fi < 8; ++fi) {
            int row = m0 + wr * 128 + fi * 16 + rq + c0;
#pragma unroll
            for (int fj = 0; fj < 4; ++fj) {
                float a0 = acc[fi][fj][0], a1 = acc[fi][fj][1], a2 = acc[fi][fj][2], a3 = acc[fi][fj][3];
                // 4x4 transpose across (lane-quad, reg): stage 1 (xor 1)
                float x0 = __shfl_xor(a1, 1, 64), x1 = __shfl_xor(a0, 1, 64);
                float x2 = __shfl_xor(a3, 1, 64), x3 = __shfl_xor(a2, 1, 64);
                bool odd = (c0 & 1) != 0;
                float t0 = odd ? x0 : a0;
                float t1 = odd ? a1 : x1;
                float t2 = odd ? x2 : a2;
                float t3 = odd ? a3 : x3;
                // stage 2 (xor 2)
                float y0 = __shfl_xor(t2, 2, 64), y2 = __shfl_xor(t0, 2, 64);
                float y1 = __shfl_xor(t3, 2, 64), y3 = __shfl_xor(t1, 2, 64);
                bool hi = (c0 & 2) != 0;
                f32x4 o;
                o[0] = hi ? y0 : t0;
                o[1] = hi ? y1 : t1;
                o[2] = hi ? t2 : y2;
                o[3] = hi ? t3 : y3;
                int cb = n0 + wc * 64 + fj * 16 + cg;
                *(f32x4*)&C[(size_t)row * NN_NODES + cb] = o;
            }
        }
    }
    if constexpr (MODE == 1) {
#pragma unroll
        for (int fi = 0; fi < 8; ++fi) {
            int rb = m0 + wr * 128 + fi * 16 + rq;
#pragma unroll
            for (int r = 0; r < 4; ++r) {
                float s = 0.f;
#pragma unroll
                for (int fj = 0; fj < 4; ++fj) s += __expf(INV_TEMP * acc[fi][fj][r]);
#pragma unroll
                for (int o = 1; o < 16; o <<= 1) s += __shfl_xor(s, o, 64);
                if ((lane & 15) == 0) atomicAdd(&zrow[rb + r], s);
            }
        }
    }
}

// ---------------- top-k: threshold prefilter + rank-based selection ----------------
__global__ __launch_bounds__(256) void topk_kernel(const float* __restrict__ S,
                                                   float* __restrict__ vals,
                                                   int* __restrict__ idxo) {
    __shared__ float sm[256];
    __shared__ int ccnt;
    __shared__ float cv[CCAP];
    __shared__ int ci[CCAP];
    __shared__ float wvs[8];
    __shared__ int wis[8];
    const int i = blockIdx.x, t = threadIdx.x;
    const int lane = t & 63, wid = t >> 6;
    const float* row = &S[(size_t)i * NN_NODES];
    float v[16];
    int id[16];
#pragma unroll
    for (int u = 0; u < 4; ++u) {
        int base = u * 1024 + t * 4;
        float4 f = *(const float4*)&row[base];
        v[u * 4 + 0] = f.x; id[u * 4 + 0] = base + 0;
        v[u * 4 + 1] = f.y; id[u * 4 + 1] = base + 1;
        v[u * 4 + 2] = f.z; id[u * 4 + 2] = base + 2;
        v[u * 4 + 3] = f.w; id[u * 4 + 3] = base + 3;
    }
    float m = v[0];
#pragma unroll
    for (int u = 1; u < 16; ++u) m = fmaxf(m, v[u]);
    sm[t] = m;
    if (t == 0) ccnt = 0;
    __syncthreads();

    // every wave: T = 17th-largest of 64 group maxima (rank via shfl loop)
    float g = fmaxf(fmaxf(sm[lane * 4 + 0], sm[lane * 4 + 1]),
                    fmaxf(sm[lane * 4 + 2], sm[lane * 4 + 3]));
    int rank = 0;
#pragma unroll
    for (int o = 1; o < 64; ++o) {
        float ov = __shfl_xor(g, o, 64);
        int ol = lane ^ o;
        if (ov > g || (ov == g && ol < lane)) rank++;
    }
    unsigned long long ball = __ballot(rank == 16);
    int tl = __ffsll((long long)ball) - 1;
    const float T = __shfl(g, tl, 64);

    // emit candidates >= T
#pragma unroll
    for (int u = 0; u < 16; ++u) {
        if (v[u] >= T) {
            int p = atomicAdd(&ccnt, 1);
            if (p < CCAP) { cv[p] = v[u]; ci[p] = id[u]; }
        }
    }
    __syncthreads();
    const int cnt = ccnt;

    if (cnt <= CCAP) {
        for (int p = t; p < cnt; p += 256) {
            float mv = cv[p];
            int mi = ci[p];
            int r = 0;
            for (int q = 0; q < cnt; ++q) {
                float qv = cv[q];
                int qi = ci[q];
                if (qv > mv || (qv == mv && qi < mi)) r++;
            }
            if (r < KTOP) {
                vals[i * KTOP + r] = isnan(mv) ? 0.f : mv;
                idxo[i * KTOP + r] = mi;
            }
        }
    } else {
        float bv = v[0];
        int bi = id[0];
#pragma unroll
        for (int u = 1; u < 16; ++u)
            if (v[u] > bv || (v[u] == bv && id[u] < bi)) { bv = v[u]; bi = id[u]; }
        for (int k = 0; k < KTOP; ++k) {
            float mv = bv;
            int mi = bi;
#pragma unroll
            for (int o = 1; o < 64; o <<= 1) {
                float ov = __shfl_xor(mv, o, 64);
                int oi = __shfl_xor(mi, o, 64);
                if (ov > mv || (ov == mv && oi < mi)) { mv = ov; mi = oi; }
            }
            int slot = ((k & 1) << 2) + wid;
            if (lane == 0) { wvs[slot] = mv; wis[slot] = mi; }
            __syncthreads();
            int b0 = (k & 1) << 2;
            mv = wvs[b0]; mi = wis[b0];
#pragma unroll
            for (int ww = 1; ww < 4; ++ww) {
                float ov = wvs[b0 + ww];
                int oi = wis[b0 + ww];
                if (ov > mv || (ov == mv && oi < mi)) { mv = ov; mi = oi; }
            }
            if (t == 0) {
                vals[i * KTOP + k] = isnan(mv) ? 0.f : mv;
                idxo[i * KTOP + k] = mi;
            }
            if (bi == mi) {
#pragma unroll
                for (int u = 0; u < 16; ++u)
                    if (id[u] == mi) v[u] = -INFINITY;
                bv = v[0]; bi = id[0];
#pragma unroll
                for (int u = 1; u < 16; ++u)
                    if (v[u] > bv || (v[u] == bv && id[u] < bi)) { bv = v[u]; bi = id[u]; }
            }
        }
    }
}

// ---------------- sparse W construction ----------------
__global__ __launch_bounds__(256) void count_indeg(const int* __restrict__ idx, int* __restrict__ cnt) {
    int e = blockIdx.x * 256 + threadIdx.x;
    if (e < NEDGE) atomicAdd(&cnt[idx[e]], 1);
}

__global__ __launch_bounds__(256) void scan_kernel(int* __restrict__ cnt, int* __restrict__ ptr) {
    __shared__ int tmp[256];
    int t = threadIdx.x;
    int base = t * 16;
    int local[16]; int s = 0;
#pragma unroll
    for (int u = 0; u < 16; ++u) { local[u] = s; s += cnt[base + u]; }
#pragma unroll
    for (int u = 0; u < 16; ++u) cnt[base + u] = 0;
    tmp[t] = s;
    __syncthreads();
    for (int off = 1; off < 256; off <<= 1) {
        int v = (t >= off) ? tmp[t - off] : 0;
        __syncthreads();
        tmp[t] += v;
        __syncthreads();
    }
    int prefix = (t > 0) ? tmp[t - 1] : 0;
#pragma unroll
    for (int u = 0; u < 16; ++u) ptr[base + u] = prefix + local[u];
    if (t == 255) ptr[NN_NODES] = prefix + s;
}

__global__ __launch_bounds__(256) void fill_rev(const int* __restrict__ idx, const float* __restrict__ vals,
                                                const int* __restrict__ ptr, int* __restrict__ fcnt,
                                                int* __restrict__ rrow, int* __restrict__ rsrc,
                                                float* __restrict__ rval) {
    int e = blockIdx.x * 256 + threadIdx.x;
    if (e >= NEDGE) return;
    int i = e / KTOP;
    int j = idx[e];
    int p = ptr[j] + atomicAdd(&fcnt[j], 1);
    rrow[p] = j; rsrc[p] = i; rval[p] = vals[e];
}

// fused fwd+rev edge weights (grid covers 2*NEDGE)
__global__ __launch_bounds__(256) void wedges_kernel(const int* __restrict__ idx, const float* __restrict__ vals,
                                                     const int* __restrict__ rrow, const int* __restrict__ rsrc,
                                                     const float* __restrict__ rval,
                                                     float* __restrict__ wfwd, float* __restrict__ wrev) {
    int e = blockIdx.x * 256 + threadIdx.x;
    if (e < NEDGE) {
        int i = e / KTOP;
        int j = idx[e];
        float a = vals[e];
        float c = 1.0f;
        const int* lj = &idx[j * KTOP];
#pragma unroll
        for (int k = 0; k < KTOP; ++k)
            if (lj[k] == i) { a += vals[j * KTOP + k]; c = 2.0f; }
        float w = a / c;
        wfwd[e] = w > 0.f ? w : 0.f;
    } else if (e < 2 * NEDGE) {
        int e2 = e - NEDGE;
        int i = rrow[e2], s = rsrc[e2];
        const int* li = &idx[i * KTOP];
        bool dup = false;
#pragma unroll
        for (int k = 0; k < KTOP; ++k)
            if (li[k] == s) dup = true;
        wrev[e2] = dup ? 0.f : fmaxf(rval[e2], 0.f);
    }
}

// out[i,:] = act(sum_j W[i,j]*X[j,:] + bias)
__global__ __launch_bounds__(256) void spmm_kernel(float* __restrict__ out, const float* __restrict__ X,
                                                   const int* __restrict__ idx, const float* __restrict__ wfwd,
                                                   const int* __restrict__ ptr, const int* __restrict__ rsrc,
                                                   const float* __restrict__ wrev,
                                                   const float* __restrict__ bias, int act) {
    int i = blockIdx.x, c = threadIdx.x;
    float acc = 0.f;
#pragma unroll
    for (int k = 0; k < KTOP; ++k) {
        int j = idx[i * KTOP + k];
        float w = wfwd[i * KTOP + k];
        acc += w * X[(size_t)j * D_H + c];
    }
    int p1 = ptr[i + 1];
    for (int p = ptr[i]; p < p1; ++p) {
        float w = wrev[p];
        if (w != 0.f) acc += w * X[(size_t)rsrc[p] * D_H + c];
    }
    acc += bias[c];
    if (act == 1) acc = fmaxf(acc, 0.f);
    else acc = acc > 0.f ? acc : expm1f(acc);
    out[(size_t)i * D_H + c] = acc;
}

// fused pf/pb over fwd+rev lists; S entries recomputed as bf16 dots (16 lanes/edge)
__global__ __launch_bounds__(256) void pfpb_edges(const unsigned short* __restrict__ z1,
                                                  const unsigned short* __restrict__ z2,
                                                  const int* __restrict__ idx,
                                                  const float* __restrict__ wfwd,
                                                  const int* __restrict__ rrow,
                                                  const int* __restrict__ rsrc,
                                                  const float* __restrict__ wrev,
                                                  const float* __restrict__ zrow,
                                                  float* __restrict__ pf, float* __restrict__ pb) {
    int g = (blockIdx.x * 256 + threadIdx.x) >> 4;  // edge id
    int l = threadIdx.x & 15;
    if (g >= 2 * NEDGE) return;
    int i, j;
    float wv;
    if (g < NEDGE) { i = g / KTOP; j = idx[g]; wv = wfwd[g]; }
    else { int e2 = g - NEDGE; i = rrow[e2]; j = rsrc[e2]; wv = wrev[e2]; }
    if (wv == 0.f) return;
    // lane l covers dims [16*l, 16*l+16)
    const uint4* a1 = (const uint4*)&z1[(size_t)i * D_H + l * 16];
    const uint4* b1 = (const uint4*)&z2[(size_t)j * D_H + l * 16];
    const uint4* a2 = (const uint4*)&z1[(size_t)j * D_H + l * 16];
    const uint4* b2 = (const uint4*)&z2[(size_t)i * D_H + l * 16];
    float s1 = dot8bf(a1[0], b1[0]) + dot8bf(a1[1], b1[1]);  // S[i][j]
    float s2 = dot8bf(a2[0], b2[0]) + dot8bf(a2[1], b2[1]);  // S[j][i]
#pragma unroll
    for (int o = 8; o > 0; o >>= 1) {
        s1 += __shfl_xor(s1, o, 64);
        s2 += __shfl_xor(s2, o, 64);
    }
    if (l == 0) {
        float pfv = expf(s1 * INV_TEMP) / zrow[i] * wv;
        float pbv = expf(s2 * INV_TEMP) / zrow[j] * wv;
        atomicAdd(&pf[i], pfv);
        atomicAdd(&pb[i], pbv);
    }
}

__global__ __launch_bounds__(256) void loss_kernel(const float* __restrict__ diag,
                                                   const float* __restrict__ zrow,
                                                   const float* __restrict__ pf,
                                                   const float* __restrict__ pb,
                                                   float* __restrict__ out) {
    __shared__ float sb[4];
    int t = threadIdx.x;
    float s = 0.f;
    for (int i = t; i < NN_NODES; i += 256) {
        float p = expf(INV_TEMP * diag[i]) / zrow[i];
        s += -logf(fmaxf(p, EPSV));
        s += 0.5f * (-logf(fmaxf(pf[i], EPSV)) - logf(fmaxf(pb[i], EPSV)));
    }
    float tot = block_reduce_sum(s, sb);
    if (t == 0) out[0] = tot / (float)NN_NODES;
}

// ---------------- launch ----------------
extern "C" void kernel_launch(void* const* d_in, const int* in_sizes, int n_in,
                              void* d_out, int out_size, void* d_ws, size_t ws_size,
                              hipStream_t stream) {
    (void)n_in; (void)out_size; (void)ws_size;
    const float* x = (const float*)d_in[0];
    const int* esrc = (const int*)d_in[1];
    const int* edst = (const int*)d_in[2];
    const float* p_feat = (const float*)d_in[3];
    const float* p_shared = (const float*)d_in[4];
    const float* p_balance = (const float*)d_in[5];
    const float* W1 = (const float*)d_in[6];
    const float* b1 = (const float*)d_in[7];
    const float* W2 = (const float*)d_in[8];
    const float* b2 = (const float*)d_in[9];
    const int E = in_sizes[1];

    float* ws = (float*)d_ws;
    size_t off = 0;
    float* SIM = ws + off; off += (size_t)NN_NODES * NN_NODES;
    float* X1  = ws + off; off += (size_t)NN_NODES * D_IN;
    float* AGG = ws + off; off += (size_t)NN_NODES * D_IN;
    float* T1  = ws + off; off += (size_t)NN_NODES * D_H;
    float* H1  = ws + off; off += (size_t)NN_NODES * D_H;
    float* T2  = ws + off; off += (size_t)NN_NODES * D_H;
    float* Z1  = ws + off; off += (size_t)NN_NODES * D_H;
    float* G1  = ws + off; off += (size_t)NN_NODES * D_H;
    float* Z2  = ws + off; off += (size_t)NN_NODES * D_H;
    float* DINV = ws + off; off += NN_NODES;
    float* VALS = ws + off; off += (size_t)NEDGE;
    int*   IDX  = (int*)(ws + off); off += (size_t)NEDGE;
    float* WFWD = ws + off; off += (size_t)NEDGE;
    int*   RPTR = (int*)(ws + off); off += NN_NODES + 1;
    int*   FCNT = (int*)(ws + off); off += NN_NODES;
    int*   RROW = (int*)(ws + off); off += (size_t)NEDGE;
    int*   RSRC = (int*)(ws + off); off += (size_t)NEDGE;
    float* RVAL = ws + off; off += (size_t)NEDGE;
    float* WREV = ws + off; off += (size_t)NEDGE;
    float* ZROW = ws + off; off += NN_NODES;   // ZROW,PF,PB contiguous (zeroed together)
    float* PF = ws + off; off += NN_NODES;
    float* PB = ws + off; off += NN_NODES;
    float* DIAG = ws + off; off += NN_NODES;
    unsigned short* HNbf = (unsigned short*)(ws + off); off += (size_t)NN_NODES * D_H / 2;
    unsigned short* Z1bf = (unsigned short*)(ws + off); off += (size_t)NN_NODES * D_H / 2;
    unsigned short* Z2bf = (unsigned short*)(ws + off); off += (size_t)NN_NODES * D_H / 2;
    int* ECNT = (int*)(ws + off); off += NN_NODES;
    int* EPTR = (int*)(ws + off); off += NN_NODES + 1;
    int* ESRT = (int*)(ws + off); off += (size_t)E;

    const int EB = (NEDGE + 255) / 256;
    const int NB = (NN_NODES + 255) / 256;
    const int EBi = (E + 255) / 256;

    // 1. x1
    x1_kernel<<<(NN_NODES * D_IN + 255) / 256, 256, 0, stream>>>(x, p_feat, p_shared, X1);
    // 2. input-graph CSR + dinv (deg = 1 + indegree)
    zero_i<<<NB, 256, 0, stream>>>(ECNT, NN_NODES);
    ecount_kernel<<<EBi, 256, 0, stream>>>(edst, ECNT, E);
    to_dinv<<<NB, 256, 0, stream>>>(ECNT, DINV);
    scan_kernel<<<1, 256, 0, stream>>>(ECNT, EPTR);  // zeroes ECNT for efill
    efill_kernel<<<EBi, 256, 0, stream>>>(esrc, edst, EPTR, ECNT, ESRT, E);
    // zero ZROW/PF/PB (contiguous)
    zero_f<<<(3 * NN_NODES + 255) / 256, 256, 0, stream>>>(ZROW, 3 * NN_NODES);
    // 3. agg = A_norm @ x1  (gather)
    prop_gather<<<NN_NODES, D_IN, 0, stream>>>(AGG, X1, DINV, EPTR, ESRT, nullptr, D_IN, 0);
    // 4. h, hn (bf16)
    h_hn_kernel<<<NN_NODES, 256, 0, stream>>>(X1, AGG, p_balance, HNbf);
    // 5. sim = hn @ hn^T  (MFMA bf16, counted-vmcnt pipeline)
    {
        dim3 g(NN_NODES / 256, NN_NODES / 256);
        gemm_nt_mfma<0><<<g, 512, 0, stream>>>(HNbf, HNbf, SIM, nullptr);
    }
    // 6. topk (threshold prefilter + rank selection)
    topk_kernel<<<NN_NODES, 256, 0, stream>>>(SIM, VALS, IDX);
    // 7. sparse W: reverse CSR + fused edge weights
    zero_i<<<NB, 256, 0, stream>>>(FCNT, NN_NODES);
    count_indeg<<<EB, 256, 0, stream>>>(IDX, FCNT);
    scan_kernel<<<1, 256, 0, stream>>>(FCNT, RPTR);  // zeroes FCNT for fill_rev
    fill_rev<<<EB, 256, 0, stream>>>(IDX, VALS, RPTR, FCNT, RROW, RSRC, RVAL);
    wedges_kernel<<<2 * EB, 256, 0, stream>>>(IDX, VALS, RROW, RSRC, RVAL, WFWD, WREV);
    // 8. t1 = x1 @ W1
    {
        dim3 g(D_H / BN, NN_NODES / BM);
        gemm_nn_kernel<<<g, 256, 0, stream>>>(X1, W1, T1, NN_NODES, D_H, D_IN, nullptr, 0);
    }
    // 9. h1 = relu(prop(t1) + b1)
    prop_gather<<<NN_NODES, D_H, 0, stream>>>(H1, T1, DINV, EPTR, ESRT, b1, D_H, 1);
    // 10. z1 = elu(prop(h1@W2) + b2)
    {
        dim3 g(D_H / BN, NN_NODES / BM);
        gemm_nn_kernel<<<g, 256, 0, stream>>>(H1, W2, T2, NN_NODES, D_H, D_H, nullptr, 0);
    }
    prop_gather<<<NN_NODES, D_H, 0, stream>>>(Z1, T2, DINV, EPTR, ESRT, b2, D_H, 2);
    // 11. g1 = relu(W @ t1 + b1)   [sparse]
    spmm_kernel<<<NN_NODES, 256, 0, stream>>>(G1, T1, IDX, WFWD, RPTR, RSRC, WREV, b1, 1);
    // 12. g2 = g1 @ W2 (into T2)
    {
        dim3 g(D_H / BN, NN_NODES / BM);
        gemm_nn_kernel<<<g, 256, 0, stream>>>(G1, W2, T2, NN_NODES, D_H, D_H, nullptr, 0);
    }
    // 13. z2 = elu(W @ g2 + b2)   [sparse]
    spmm_kernel<<<NN_NODES, 256, 0, stream>>>(Z2, T2, IDX, WFWD, RPTR, RSRC, WREV, b2, 2);
    // 14. normalize z1, z2 -> bf16 (single launch), then diag dots
    rownorm2_kernel<<<2 * NN_NODES, 256, 0, stream>>>(Z1, Z1bf, Z2, Z2bf);
    diag_kernel<<<NN_NODES / 4, 256, 0, stream>>>(Z1bf, Z2bf, DIAG);
    // 15. zrow only: row-sums of exp(5 * z1n@z2n^T) — no 67 MB S materialization
    {
        dim3 g(NN_NODES / 256, NN_NODES / 256);
        gemm_nt_mfma<1><<<g, 512, 0, stream>>>(Z1bf, Z2bf, nullptr, ZROW);
    }
    // 16. pf / pb (fused fwd+rev, S entries recomputed from bf16 rows in L2)
    {
        int blocks = (2 * NEDGE * 16 + 255) / 256;
        pfpb_edges<<<blocks, 256, 0, stream>>>(Z1bf, Z2bf, IDX, WFWD, RROW, RSRC, WREV, ZROW, PF, PB);
    }
    // 17. loss
    loss_kernel<<<1, 256, 0, stream>>>(DIAG, ZROW, PF, PB, (float*)d_out);
}

// Round 6
// 380.685 us; speedup vs baseline: 1.1798x; 1.0980x over previous
//
#include <hip/hip_runtime.h>
#include <math.h>

#define NN_NODES 4096
#define D_IN 128
#define D_H 256
#define KTOP 17
#define NEDGE (NN_NODES * KTOP)
#define INV_TEMP 5.0f
#define EPSV 1e-8f
#define CCAP 1024

typedef __bf16 bf16x8 __attribute__((ext_vector_type(8)));
typedef float f32x4 __attribute__((ext_vector_type(4)));

// ---------------- helpers ----------------
__device__ __forceinline__ float block_reduce_sum(float v, float* sb) {
#pragma unroll
    for (int o = 32; o > 0; o >>= 1) v += __shfl_down(v, o, 64);
    int wid = threadIdx.x >> 6;
    __syncthreads();
    if ((threadIdx.x & 63) == 0) sb[wid] = v;
    __syncthreads();
    return sb[0] + sb[1] + sb[2] + sb[3];
}

// fp32 -> bf16 (RNE)
__device__ __forceinline__ unsigned short f2bf(float x) {
    unsigned u = __float_as_uint(x);
    unsigned r = u + 0x7fff + ((u >> 16) & 1);
    return (unsigned short)(r >> 16);
}

__device__ __forceinline__ float bflo(unsigned x) { return __uint_as_float(x << 16); }
__device__ __forceinline__ float bfhi(unsigned x) { return __uint_as_float(x & 0xffff0000u); }

__device__ __forceinline__ float dot8bf(uint4 a, uint4 b) {
    float s = bflo(a.x) * bflo(b.x) + bfhi(a.x) * bfhi(b.x);
    s += bflo(a.y) * bflo(b.y) + bfhi(a.y) * bfhi(b.y);
    s += bflo(a.z) * bflo(b.z) + bfhi(a.z) * bfhi(b.z);
    s += bflo(a.w) * bflo(b.w) + bfhi(a.w) * bfhi(b.w);
    return s;
}

// async global -> LDS, 16 bytes per lane (wave-uniform LDS base + lane*16)
__device__ __forceinline__ void gl_lds16(const void* g, void* l) {
    __builtin_amdgcn_global_load_lds(
        (const __attribute__((address_space(1))) void*)(g),
        (__attribute__((address_space(3))) void*)(l), 16, 0, 0);
}

#define BARRIER_SB() do { __builtin_amdgcn_s_barrier(); __builtin_amdgcn_sched_barrier(0); } while (0)
#define WAITV(n) do { asm volatile("s_waitcnt vmcnt(" #n ")" ::: "memory"); __builtin_amdgcn_sched_barrier(0); } while (0)

// ---------------- fused setup: x1 elementwise + zero(ECNT, FCNT, ZROW/PF/PB) ----------------
__global__ __launch_bounds__(256) void setup_kernel(const float* __restrict__ x,
                                                    const float* __restrict__ p_feat,
                                                    const float* __restrict__ p_shared,
                                                    float* __restrict__ x1,
                                                    int* __restrict__ ecnt,
                                                    int* __restrict__ fcnt,
                                                    float* __restrict__ zpp) {
    int i = blockIdx.x * 256 + threadIdx.x;
    if (i < NN_NODES * D_IN) {
        int c = i & (D_IN - 1);
        float v = x[i] * p_feat[c];
        v = fmaxf(v, 0.0f) * p_shared[c];
        x1[i] = v;
        return;
    }
    int z = i - NN_NODES * D_IN;
    if (z < NN_NODES) ecnt[z] = 0;
    else if (z < 2 * NN_NODES) fcnt[z - NN_NODES] = 0;
    else if (z < 5 * NN_NODES) zpp[z - 2 * NN_NODES] = 0.f;  // ZROW,PF,PB contiguous
}

// ---------------- input-graph CSR (keyed by dst) ----------------
__global__ __launch_bounds__(256) void ecount_kernel(const int* __restrict__ dst, int* __restrict__ cnt, int E) {
    int e = blockIdx.x * 256 + threadIdx.x;
    if (e < E) atomicAdd(&cnt[dst[e]], 1);
}

// exclusive scan of 4096 counts -> ptr[4097]; zeroes cnt; optional dinv=rsqrt(1+cnt)
__global__ __launch_bounds__(256) void scan_kernel(int* __restrict__ cnt, int* __restrict__ ptr,
                                                   float* __restrict__ dinv) {
    __shared__ int tmp[256];
    int t = threadIdx.x;
    int base = t * 16;
    int c[16]; int local[16]; int s = 0;
#pragma unroll
    for (int u = 0; u < 16; ++u) { c[u] = cnt[base + u]; local[u] = s; s += c[u]; cnt[base + u] = 0; }
    if (dinv) {
#pragma unroll
        for (int u = 0; u < 16; ++u) dinv[base + u] = rsqrtf(1.0f + (float)c[u]);
    }
    tmp[t] = s;
    __syncthreads();
    for (int off = 1; off < 256; off <<= 1) {
        int v = (t >= off) ? tmp[t - off] : 0;
        __syncthreads();
        tmp[t] += v;
        __syncthreads();
    }
    int prefix = (t > 0) ? tmp[t - 1] : 0;
#pragma unroll
    for (int u = 0; u < 16; ++u) ptr[base + u] = prefix + local[u];
    if (t == 255) ptr[NN_NODES] = prefix + s;
}

__global__ __launch_bounds__(256) void efill_kernel(const int* __restrict__ src, const int* __restrict__ dst,
                                                    const int* __restrict__ ptr, int* __restrict__ cnt,
                                                    int* __restrict__ esrt, int E) {
    int e = blockIdx.x * 256 + threadIdx.x;
    if (e >= E) return;
    int d = dst[e];
    int p = ptr[d] + atomicAdd(&cnt[d], 1);
    esrt[p] = src[e];
}

// ---------------- fused: agg gather + h/hn normalize -> bf16 ----------------
// block n, 256 threads: t<128 -> x1 part; t>=128 -> gather agg channel (t-128).
__global__ __launch_bounds__(256) void agg_hn_kernel(const float* __restrict__ x1,
                                                     const float* __restrict__ dinv,
                                                     const int* __restrict__ eptr,
                                                     const int* __restrict__ esrt,
                                                     const float* __restrict__ p_balance,
                                                     unsigned short* __restrict__ hn_bf) {
    __shared__ float sb[4];
    int n = blockIdx.x, t = threadIdx.x;
    float v;
    if (t < D_IN) {
        v = x1[(size_t)n * D_IN + t] * p_balance[t];
    } else {
        int c = t - D_IN;
        float dn = dinv[n];
        float acc = dn * dn * x1[(size_t)n * D_IN + c];
        int p1 = eptr[n + 1];
        for (int p = eptr[n]; p < p1; ++p) {
            int s = esrt[p];
            acc += dinv[s] * dn * x1[(size_t)s * D_IN + c];
        }
        v = acc * p_balance[t];
    }
    float ss = block_reduce_sum(v * v, sb);
    float inv = 1.0f / (sqrtf(ss) + EPSV);
    hn_bf[(size_t)n * D_H + t] = f2bf(v * inv);
}

// ---------------- fused: rownorm both Z + diag dot ----------------
__global__ __launch_bounds__(256) void rownorm_diag_kernel(const float* __restrict__ Z1,
                                                           const float* __restrict__ Z2,
                                                           unsigned short* __restrict__ z1bf,
                                                           unsigned short* __restrict__ z2bf,
                                                           float* __restrict__ diag) {
    __shared__ float sb[4];
    int n = blockIdx.x, t = threadIdx.x;
    float v1 = Z1[(size_t)n * D_H + t];
    float v2 = Z2[(size_t)n * D_H + t];
    float ss1 = block_reduce_sum(v1 * v1, sb);
    float ss2 = block_reduce_sum(v2 * v2, sb);
    float i1 = 1.0f / (sqrtf(ss1) + EPSV);
    float i2 = 1.0f / (sqrtf(ss2) + EPSV);
    z1bf[(size_t)n * D_H + t] = f2bf(v1 * i1);
    z2bf[(size_t)n * D_H + t] = f2bf(v2 * i2);
    float d = block_reduce_sum((v1 * i1) * (v2 * i2), sb);
    if (t == 0) diag[n] = d;
}

// ---------------- fp32 GEMM (small NN cases) ----------------
#define BM 64
#define BN 64
#define BK 16

__device__ __forceinline__ void gemm_nn_body(const float* __restrict__ A, const float* __restrict__ B,
                                             float* __restrict__ C, int Nn, int Kk, int m0, int n0) {
    __shared__ float As[BK][BM + 4];
    __shared__ float Bs[BK][BN + 4];
    const int tid = threadIdx.x;
    const int tx = tid & 15, ty = tid >> 4;
    const int arow = tid >> 2, acol = (tid & 3) << 2;
    const int brow = tid >> 4, bcol = (tid & 15) << 2;
    float acc[4][4] = {{0.f}};

    for (int k0 = 0; k0 < Kk; k0 += BK) {
        float4 av = *(const float4*)&A[(size_t)(m0 + arow) * Kk + k0 + acol];
        float4 bv = *(const float4*)&B[(size_t)(k0 + brow) * Nn + n0 + bcol];
        As[acol + 0][arow] = av.x;
        As[acol + 1][arow] = av.y;
        As[acol + 2][arow] = av.z;
        As[acol + 3][arow] = av.w;
        *(float4*)&Bs[brow][bcol] = bv;
        __syncthreads();
#pragma unroll
        for (int k = 0; k < BK; ++k) {
            float4 a = *(const float4*)&As[k][ty << 2];
            float4 b = *(const float4*)&Bs[k][tx << 2];
            acc[0][0] += a.x * b.x; acc[0][1] += a.x * b.y; acc[0][2] += a.x * b.z; acc[0][3] += a.x * b.w;
            acc[1][0] += a.y * b.x; acc[1][1] += a.y * b.y; acc[1][2] += a.y * b.z; acc[1][3] += a.y * b.w;
            acc[2][0] += a.z * b.x; acc[2][1] += a.z * b.y; acc[2][2] += a.z * b.z; acc[2][3] += a.z * b.w;
            acc[3][0] += a.w * b.x; acc[3][1] += a.w * b.y; acc[3][2] += a.w * b.z; acc[3][3] += a.w * b.w;
        }
        __syncthreads();
    }
#pragma unroll
    for (int i = 0; i < 4; ++i) {
        int m = m0 + (ty << 2) + i;
        *(float4*)&C[(size_t)m * Nn + n0 + (tx << 2)] = *(float4*)acc[i];
    }
}

__global__ __launch_bounds__(256) void gemm_nn_kernel(const float* __restrict__ A,
                                                      const float* __restrict__ B,
                                                      float* __restrict__ C, int Nn, int Kk) {
    gemm_nn_body(A, B, C, Nn, Kk, blockIdx.y * BM, blockIdx.x * BN);
}

// two M=4096,N=256,K=256 GEMMs in one launch (grid y doubled)
__global__ __launch_bounds__(256) void gemm_nn2x_kernel(const float* __restrict__ A1,
                                                        const float* __restrict__ A2,
                                                        const float* __restrict__ B,
                                                        float* __restrict__ C1,
                                                        float* __restrict__ C2) {
    int gy = blockIdx.y;
    const float* A = (gy < NN_NODES / BM) ? A1 : A2;
    float* C = (gy < NN_NODES / BM) ? C1 : C2;
    int m0 = (gy & (NN_NODES / BM - 1)) * BM;
    gemm_nn_body(A, B, C, D_H, D_H, m0, blockIdx.x * BN);
}

// ---------------- MFMA NT GEMM: C[4096,4096] = X @ Y^T, K=256, single bf16 ----------------
// 256x256 tile, 8 waves, BK=64, dbuf 128 KB LDS, counted-vmcnt pipeline (T4).
// MODE 0: write C. MODE 1: zrow-only (row-sums of exp(5*S)).
template <int MODE>
__global__ __launch_bounds__(512) void gemm_nt_mfma(const unsigned short* __restrict__ Abf,
                                                    const unsigned short* __restrict__ Bbf,
                                                    float* __restrict__ C,
                                                    float* __restrict__ zrow) {
    __shared__ char lds[131072];
    const int tid = threadIdx.x;
    const int w = tid >> 6, lane = tid & 63;
    const int wr = w >> 2, wc = w & 3;
    const int m0 = blockIdx.y * 256, n0 = blockIdx.x * 256;
    const int lrow = lane & 15, lquad = lane >> 4;

    f32x4 acc[8][4];
#pragma unroll
    for (int i = 0; i < 8; ++i)
#pragma unroll
        for (int j = 0; j < 4; ++j) acc[i][j] = (f32x4)(0.f);

    const char* Ag = (const char*)Abf + (size_t)m0 * 512;
    const char* Bg = (const char*)Bbf + (size_t)n0 * 512;

    const int ssub = ((lane & 7) << 4) ^ (((lane >> 3) & 7) << 4);
    auto stage = [&](int half, int k0) {
        char* Abuf = lds + half * 65536;
        char* Bbuf = Abuf + 32768;
#pragma unroll
        for (int ti = 0; ti < 4; ++ti) {
            int chunk = ti * 8 + w;
            int row = chunk * 8 + (lane >> 3);
            size_t gb = (size_t)row * 512 + (size_t)k0 * 2 + ssub;
            gl_lds16(Ag + gb, Abuf + chunk * 1024);
            gl_lds16(Bg + gb, Bbuf + chunk * 1024);
        }
    };

    auto compute = [&](int half) {
        const char* Abuf = lds + half * 65536;
        const char* Bbuf = Abuf + 32768;
#pragma unroll
        for (int ksub = 0; ksub < 2; ++ksub) {
            int co = (ksub * 64 + lquad * 16) ^ ((lrow & 7) << 4);
            bf16x8 a[8], b[4];
#pragma unroll
            for (int fi = 0; fi < 8; ++fi) {
                int row = wr * 128 + fi * 16 + lrow;
                a[fi] = __builtin_bit_cast(bf16x8, *(const uint4*)(Abuf + row * 128 + co));
            }
#pragma unroll
            for (int fj = 0; fj < 4; ++fj) {
                int row = wc * 64 + fj * 16 + lrow;
                b[fj] = __builtin_bit_cast(bf16x8, *(const uint4*)(Bbuf + row * 128 + co));
            }
#pragma unroll
            for (int fi = 0; fi < 8; ++fi)
#pragma unroll
                for (int fj = 0; fj < 4; ++fj)
                    acc[fi][fj] = __builtin_amdgcn_mfma_f32_16x16x32_bf16(a[fi], b[fj], acc[fi][fj], 0, 0, 0);
        }
    };

    stage(0, 0);
    stage(1, 64);
    WAITV(8); BARRIER_SB();
    compute(0);
    BARRIER_SB();
    stage(0, 128);
    WAITV(8); BARRIER_SB();
    compute(1);
    BARRIER_SB();
    stage(1, 192);
    WAITV(8); BARRIER_SB();
    compute(0);
    BARRIER_SB();
    WAITV(0); BARRIER_SB();
    compute(1);

    const int rq = (lane >> 4) * 4;
    if constexpr (MODE == 0) {
        const int c0 = lane & 3;
        const int cg = ((lane & 15) >> 2) << 2;
#pragma unroll
        for (int fi = 0; fi < 8; ++fi) {
            int row = m0 + wr * 128 + fi * 16 + rq + c0;
#pragma unroll
            for (int fj = 0; fj < 4; ++fj) {
                float a0 = acc[fi][fj][0], a1 = acc[fi][fj][1], a2 = acc[fi][fj][2], a3 = acc[fi][fj][3];
                float x0 = __shfl_xor(a1, 1, 64), x1 = __shfl_xor(a0, 1, 64);
                float x2 = __shfl_xor(a3, 1, 64), x3 = __shfl_xor(a2, 1, 64);
                bool odd = (c0 & 1) != 0;
                float t0 = odd ? x0 : a0;
                float t1 = odd ? a1 : x1;
                float t2 = odd ? x2 : a2;
                float t3 = odd ? a3 : x3;
                float y0 = __shfl_xor(t2, 2, 64), y2 = __shfl_xor(t0, 2, 64);
                float y1 = __shfl_xor(t3, 2, 64), y3 = __shfl_xor(t1, 2, 64);
                bool hi = (c0 & 2) != 0;
                f32x4 o;
                o[0] = hi ? y0 : t0;
                o[1] = hi ? y1 : t1;
                o[2] = hi ? t2 : y2;
                o[3] = hi ? t3 : y3;
                int cb = n0 + wc * 64 + fj * 16 + cg;
                *(f32x4*)&C[(size_t)row * NN_NODES + cb] = o;
            }
        }
    }
    if constexpr (MODE == 1) {
#pragma unroll
        for (int fi = 0; fi < 8; ++fi) {
            int rb = m0 + wr * 128 + fi * 16 + rq;
#pragma unroll
            for (int r = 0; r < 4; ++r) {
                float s = 0.f;
#pragma unroll
                for (int fj = 0; fj < 4; ++fj) s += __expf(INV_TEMP * acc[fi][fj][r]);
#pragma unroll
                for (int o = 1; o < 16; o <<= 1) s += __shfl_xor(s, o, 64);
                if ((lane & 15) == 0) atomicAdd(&zrow[rb + r], s);
            }
        }
    }
}

// ---------------- top-k (+ fused indegree count of selected indices) ----------------
__global__ __launch_bounds__(256) void topk_kernel(const float* __restrict__ S,
                                                   float* __restrict__ vals,
                                                   int* __restrict__ idxo,
                                                   int* __restrict__ fcnt) {
    __shared__ float sm[256];
    __shared__ int ccnt;
    __shared__ float cv[CCAP];
    __shared__ int ci[CCAP];
    __shared__ float wvs[8];
    __shared__ int wis[8];
    const int i = blockIdx.x, t = threadIdx.x;
    const int lane = t & 63, wid = t >> 6;
    const float* row = &S[(size_t)i * NN_NODES];
    float v[16];
    int id[16];
#pragma unroll
    for (int u = 0; u < 4; ++u) {
        int base = u * 1024 + t * 4;
        float4 f = *(const float4*)&row[base];
        v[u * 4 + 0] = f.x; id[u * 4 + 0] = base + 0;
        v[u * 4 + 1] = f.y; id[u * 4 + 1] = base + 1;
        v[u * 4 + 2] = f.z; id[u * 4 + 2] = base + 2;
        v[u * 4 + 3] = f.w; id[u * 4 + 3] = base + 3;
    }
    float m = v[0];
#pragma unroll
    for (int u = 1; u < 16; ++u) m = fmaxf(m, v[u]);
    sm[t] = m;
    if (t == 0) ccnt = 0;
    __syncthreads();

    float g = fmaxf(fmaxf(sm[lane * 4 + 0], sm[lane * 4 + 1]),
                    fmaxf(sm[lane * 4 + 2], sm[lane * 4 + 3]));
    int rank = 0;
#pragma unroll
    for (int o = 1; o < 64; ++o) {
        float ov = __shfl_xor(g, o, 64);
        int ol = lane ^ o;
        if (ov > g || (ov == g && ol < lane)) rank++;
    }
    unsigned long long ball = __ballot(rank == 16);
    int tl = __ffsll((long long)ball) - 1;
    const float T = __shfl(g, tl, 64);

#pragma unroll
    for (int u = 0; u < 16; ++u) {
        if (v[u] >= T) {
            int p = atomicAdd(&ccnt, 1);
            if (p < CCAP) { cv[p] = v[u]; ci[p] = id[u]; }
        }
    }
    __syncthreads();
    const int cnt = ccnt;

    if (cnt <= CCAP) {
        for (int p = t; p < cnt; p += 256) {
            float mv = cv[p];
            int mi = ci[p];
            int r = 0;
            for (int q = 0; q < cnt; ++q) {
                float qv = cv[q];
                int qi = ci[q];
                if (qv > mv || (qv == mv && qi < mi)) r++;
            }
            if (r < KTOP) {
                vals[i * KTOP + r] = isnan(mv) ? 0.f : mv;
                idxo[i * KTOP + r] = mi;
                atomicAdd(&fcnt[mi], 1);
            }
        }
    } else {
        float bv = v[0];
        int bi = id[0];
#pragma unroll
        for (int u = 1; u < 16; ++u)
            if (v[u] > bv || (v[u] == bv && id[u] < bi)) { bv = v[u]; bi = id[u]; }
        for (int k = 0; k < KTOP; ++k) {
            float mv = bv;
            int mi = bi;
#pragma unroll
            for (int o = 1; o < 64; o <<= 1) {
                float ov = __shfl_xor(mv, o, 64);
                int oi = __shfl_xor(mi, o, 64);
                if (ov > mv || (ov == mv && oi < mi)) { mv = ov; mi = oi; }
            }
            int slot = ((k & 1) << 2) + wid;
            if (lane == 0) { wvs[slot] = mv; wis[slot] = mi; }
            __syncthreads();
            int b0 = (k & 1) << 2;
            mv = wvs[b0]; mi = wis[b0];
#pragma unroll
            for (int ww = 1; ww < 4; ++ww) {
                float ov = wvs[b0 + ww];
                int oi = wis[b0 + ww];
                if (ov > mv || (ov == mv && oi < mi)) { mv = ov; mi = oi; }
            }
            if (t == 0) {
                vals[i * KTOP + k] = isnan(mv) ? 0.f : mv;
                idxo[i * KTOP + k] = mi;
                atomicAdd(&fcnt[mi], 1);
            }
            if (bi == mi) {
#pragma unroll
                for (int u = 0; u < 16; ++u)
                    if (id[u] == mi) v[u] = -INFINITY;
                bv = v[0]; bi = id[0];
#pragma unroll
                for (int u = 1; u < 16; ++u)
                    if (v[u] > bv || (v[u] == bv && id[u] < bi)) { bv = v[u]; bi = id[u]; }
            }
        }
    }
}

// ---------------- fused: reverse-CSR fill + fwd/rev edge weights ----------------
__global__ __launch_bounds__(256) void fillrev_wedges(const int* __restrict__ idx,
                                                      const float* __restrict__ vals,
                                                      const int* __restrict__ ptr,
                                                      int* __restrict__ fcnt,
                                                      int* __restrict__ rrow, int* __restrict__ rsrc,
                                                      float* __restrict__ wrev,
                                                      float* __restrict__ wfwd) {
    int e = blockIdx.x * 256 + threadIdx.x;
    if (e >= NEDGE) return;
    int i = e / KTOP;
    int j = idx[e];
    float a = vals[e];
    bool found = false;
    float bval = 0.f;
    const int* lj = &idx[j * KTOP];
#pragma unroll
    for (int k = 0; k < KTOP; ++k)
        if (lj[k] == i) { found = true; bval = vals[j * KTOP + k]; }
    float w = (a + (found ? bval : 0.f)) / (found ? 2.0f : 1.0f);
    wfwd[e] = w > 0.f ? w : 0.f;
    int p = ptr[j] + atomicAdd(&fcnt[j], 1);
    rrow[p] = j; rsrc[p] = i;
    wrev[p] = found ? 0.f : fmaxf(a, 0.f);
}

// ---------------- dual prop/spmm rows (one launch, grid 2*NN) ----------------
__device__ __forceinline__ void prop_row(float* __restrict__ out, const float* __restrict__ h,
                                         const float* __restrict__ dinv, const int* __restrict__ eptr,
                                         const int* __restrict__ esrt, const float* __restrict__ bias,
                                         int n, int act) {
    int t = threadIdx.x;
    float dn = dinv[n];
    float acc = dn * dn * h[(size_t)n * D_H + t];
    int p1 = eptr[n + 1];
    for (int p = eptr[n]; p < p1; ++p) {
        int s = esrt[p];
        acc += dinv[s] * dn * h[(size_t)s * D_H + t];
    }
    acc += bias[t];
    if (act == 1) acc = fmaxf(acc, 0.f);
    else acc = acc > 0.f ? acc : expm1f(acc);
    out[(size_t)n * D_H + t] = acc;
}

__device__ __forceinline__ void spmm_row(float* __restrict__ out, const float* __restrict__ X,
                                         const int* __restrict__ idx, const float* __restrict__ wfwd,
                                         const int* __restrict__ ptr, const int* __restrict__ rsrc,
                                         const float* __restrict__ wrev, const float* __restrict__ bias,
                                         int i, int act) {
    int c = threadIdx.x;
    float acc = 0.f;
#pragma unroll
    for (int k = 0; k < KTOP; ++k) {
        int j = idx[i * KTOP + k];
        float w = wfwd[i * KTOP + k];
        acc += w * X[(size_t)j * D_H + c];
    }
    int p1 = ptr[i + 1];
    for (int p = ptr[i]; p < p1; ++p) {
        float w = wrev[p];
        if (w != 0.f) acc += w * X[(size_t)rsrc[p] * D_H + c];
    }
    acc += bias[c];
    if (act == 1) acc = fmaxf(acc, 0.f);
    else acc = acc > 0.f ? acc : expm1f(acc);
    out[(size_t)i * D_H + c] = acc;
}

// blocks [0,NN): out1 = act(prop(Xp)); blocks [NN,2NN): out2 = act(W @ Xs)
__global__ __launch_bounds__(256) void dual_prop_spmm(const float* __restrict__ Xp,
                                                      const float* __restrict__ Xs,
                                                      const float* __restrict__ dinv,
                                                      const int* __restrict__ eptr,
                                                      const int* __restrict__ esrt,
                                                      const int* __restrict__ idx,
                                                      const float* __restrict__ wfwd,
                                                      const int* __restrict__ rptr,
                                                      const int* __restrict__ rsrc,
                                                      const float* __restrict__ wrev,
                                                      const float* __restrict__ bias,
                                                      float* __restrict__ out1,
                                                      float* __restrict__ out2,
                                                      int act) {
    int b = blockIdx.x;
    if (b < NN_NODES) prop_row(out1, Xp, dinv, eptr, esrt, bias, b, act);
    else spmm_row(out2, Xs, idx, wfwd, rptr, rsrc, wrev, bias, b - NN_NODES, act);
}

// ---------------- pf/pb (edge dots from L2-resident bf16 rows) ----------------
__global__ __launch_bounds__(256) void pfpb_edges(const unsigned short* __restrict__ z1,
                                                  const unsigned short* __restrict__ z2,
                                                  const int* __restrict__ idx,
                                                  const float* __restrict__ wfwd,
                                                  const int* __restrict__ rrow,
                                                  const int* __restrict__ rsrc,
                                                  const float* __restrict__ wrev,
                                                  const float* __restrict__ zrow,
                                                  float* __restrict__ pf, float* __restrict__ pb) {
    int g = (blockIdx.x * 256 + threadIdx.x) >> 4;
    int l = threadIdx.x & 15;
    if (g >= 2 * NEDGE) return;
    int i, j;
    float wv;
    if (g < NEDGE) { i = g / KTOP; j = idx[g]; wv = wfwd[g]; }
    else { int e2 = g - NEDGE; i = rrow[e2]; j = rsrc[e2]; wv = wrev[e2]; }
    if (wv == 0.f) return;
    const uint4* a1 = (const uint4*)&z1[(size_t)i * D_H + l * 16];
    const uint4* b1 = (const uint4*)&z2[(size_t)j * D_H + l * 16];
    const uint4* a2 = (const uint4*)&z1[(size_t)j * D_H + l * 16];
    const uint4* b2 = (const uint4*)&z2[(size_t)i * D_H + l * 16];
    float s1 = dot8bf(a1[0], b1[0]) + dot8bf(a1[1], b1[1]);
    float s2 = dot8bf(a2[0], b2[0]) + dot8bf(a2[1], b2[1]);
#pragma unroll
    for (int o = 8; o > 0; o >>= 1) {
        s1 += __shfl_xor(s1, o, 64);
        s2 += __shfl_xor(s2, o, 64);
    }
    if (l == 0) {
        float pfv = expf(s1 * INV_TEMP) / zrow[i] * wv;
        float pbv = expf(s2 * INV_TEMP) / zrow[j] * wv;
        atomicAdd(&pf[i], pfv);
        atomicAdd(&pb[i], pbv);
    }
}

__global__ __launch_bounds__(256) void loss_kernel(const float* __restrict__ diag,
                                                   const float* __restrict__ zrow,
                                                   const float* __restrict__ pf,
                                                   const float* __restrict__ pb,
                                                   float* __restrict__ out) {
    __shared__ float sb[4];
    int t = threadIdx.x;
    float s = 0.f;
    for (int i = t; i < NN_NODES; i += 256) {
        float p = expf(INV_TEMP * diag[i]) / zrow[i];
        s += -logf(fmaxf(p, EPSV));
        s += 0.5f * (-logf(fmaxf(pf[i], EPSV)) - logf(fmaxf(pb[i], EPSV)));
    }
    float tot = block_reduce_sum(s, sb);
    if (t == 0) out[0] = tot / (float)NN_NODES;
}

// ---------------- launch ----------------
extern "C" void kernel_launch(void* const* d_in, const int* in_sizes, int n_in,
                              void* d_out, int out_size, void* d_ws, size_t ws_size,
                              hipStream_t stream) {
    (void)n_in; (void)out_size; (void)ws_size;
    const float* x = (const float*)d_in[0];
    const int* esrc = (const int*)d_in[1];
    const int* edst = (const int*)d_in[2];
    const float* p_feat = (const float*)d_in[3];
    const float* p_shared = (const float*)d_in[4];
    const float* p_balance = (const float*)d_in[5];
    const float* W1 = (const float*)d_in[6];
    const float* b1 = (const float*)d_in[7];
    const float* W2 = (const float*)d_in[8];
    const float* b2 = (const float*)d_in[9];
    const int E = in_sizes[1];

    float* ws = (float*)d_ws;
    size_t off = 0;
    float* SIM = ws + off; off += (size_t)NN_NODES * NN_NODES;
    float* X1  = ws + off; off += (size_t)NN_NODES * D_IN;
    float* T1  = ws + off; off += (size_t)NN_NODES * D_H;
    float* H1  = ws + off; off += (size_t)NN_NODES * D_H;
    float* T2  = ws + off; off += (size_t)NN_NODES * D_H;
    float* T3  = ws + off; off += (size_t)NN_NODES * D_H;
    float* Z1  = ws + off; off += (size_t)NN_NODES * D_H;
    float* G1  = ws + off; off += (size_t)NN_NODES * D_H;
    float* Z2  = ws + off; off += (size_t)NN_NODES * D_H;
    float* DINV = ws + off; off += NN_NODES;
    float* VALS = ws + off; off += (size_t)NEDGE;
    int*   IDX  = (int*)(ws + off); off += (size_t)NEDGE;
    float* WFWD = ws + off; off += (size_t)NEDGE;
    int*   RPTR = (int*)(ws + off); off += NN_NODES + 1;
    int*   FCNT = (int*)(ws + off); off += NN_NODES;
    int*   RROW = (int*)(ws + off); off += (size_t)NEDGE;
    int*   RSRC = (int*)(ws + off); off += (size_t)NEDGE;
    float* WREV = ws + off; off += (size_t)NEDGE;
    float* ZROW = ws + off; off += NN_NODES;   // ZROW,PF,PB contiguous (zeroed together)
    float* PF = ws + off; off += NN_NODES;
    float* PB = ws + off; off += NN_NODES;
    float* DIAG = ws + off; off += NN_NODES;
    unsigned short* HNbf = (unsigned short*)(ws + off); off += (size_t)NN_NODES * D_H / 2;
    unsigned short* Z1bf = (unsigned short*)(ws + off); off += (size_t)NN_NODES * D_H / 2;
    unsigned short* Z2bf = (unsigned short*)(ws + off); off += (size_t)NN_NODES * D_H / 2;
    int* ECNT = (int*)(ws + off); off += NN_NODES;
    int* EPTR = (int*)(ws + off); off += NN_NODES + 1;
    int* ESRT = (int*)(ws + off); off += (size_t)E;

    const int EB = (NEDGE + 255) / 256;
    const int EBi = (E + 255) / 256;

    // 1. setup: x1 + zero(ECNT, FCNT, ZROW/PF/PB)   [was 4 launches]
    {
        int blocks = (NN_NODES * D_IN + 5 * NN_NODES + 255) / 256;
        setup_kernel<<<blocks, 256, 0, stream>>>(x, p_feat, p_shared, X1, ECNT, FCNT, ZROW);
    }
    // 2. indegree count
    ecount_kernel<<<EBi, 256, 0, stream>>>(edst, ECNT, E);
    // 3. scan + dinv   [was 2 launches]
    scan_kernel<<<1, 256, 0, stream>>>(ECNT, EPTR, DINV);
    // 4. CSR fill
    efill_kernel<<<EBi, 256, 0, stream>>>(esrc, edst, EPTR, ECNT, ESRT, E);
    // 5. agg gather + h/hn -> bf16   [was 2 launches, AGG buffer eliminated]
    agg_hn_kernel<<<NN_NODES, 256, 0, stream>>>(X1, DINV, EPTR, ESRT, p_balance, HNbf);
    // 6. sim = hn @ hn^T
    {
        dim3 g(NN_NODES / 256, NN_NODES / 256);
        gemm_nt_mfma<0><<<g, 512, 0, stream>>>(HNbf, HNbf, SIM, nullptr);
    }
    // 7. topk + fused indegree count of selected   [was 2 launches]
    topk_kernel<<<NN_NODES, 256, 0, stream>>>(SIM, VALS, IDX, FCNT);
    // 8. scan (FCNT -> RPTR, zeroes FCNT)
    scan_kernel<<<1, 256, 0, stream>>>(FCNT, RPTR, nullptr);
    // 9. reverse fill + fwd/rev edge weights   [was 2 launches, RVAL eliminated]
    fillrev_wedges<<<EB, 256, 0, stream>>>(IDX, VALS, RPTR, FCNT, RROW, RSRC, WREV, WFWD);
    // 10. t1 = x1 @ W1
    {
        dim3 g(D_H / BN, NN_NODES / BM);
        gemm_nn_kernel<<<g, 256, 0, stream>>>(X1, W1, T1, D_H, D_IN);
    }
    // 11. H1 = relu(prop(T1)+b1)  ||  G1 = relu(W@T1+b1)   [was 2 launches]
    dual_prop_spmm<<<2 * NN_NODES, 256, 0, stream>>>(T1, T1, DINV, EPTR, ESRT, IDX, WFWD,
                                                     RPTR, RSRC, WREV, b1, H1, G1, 1);
    // 12. T2 = H1 @ W2  ||  T3 = G1 @ W2   [was 2 launches]
    {
        dim3 g(D_H / BN, 2 * NN_NODES / BM);
        gemm_nn2x_kernel<<<g, 256, 0, stream>>>(H1, G1, W2, T2, T3);
    }
    // 13. Z1 = elu(prop(T2)+b2)  ||  Z2 = elu(W@T3+b2)   [was 2 launches]
    dual_prop_spmm<<<2 * NN_NODES, 256, 0, stream>>>(T2, T3, DINV, EPTR, ESRT, IDX, WFWD,
                                                     RPTR, RSRC, WREV, b2, Z1, Z2, 2);
    // 14. rownorm both -> bf16 + diag   [was 2 launches]
    rownorm_diag_kernel<<<NN_NODES, 256, 0, stream>>>(Z1, Z2, Z1bf, Z2bf, DIAG);
    // 15. zrow: row-sums of exp(5 * z1n@z2n^T)
    {
        dim3 g(NN_NODES / 256, NN_NODES / 256);
        gemm_nt_mfma<1><<<g, 512, 0, stream>>>(Z1bf, Z2bf, nullptr, ZROW);
    }
    // 16. pf / pb
    {
        int blocks = (2 * NEDGE * 16 + 255) / 256;
        pfpb_edges<<<blocks, 256, 0, stream>>>(Z1bf, Z2bf, IDX, WFWD, RROW, RSRC, WREV, ZROW, PF, PB);
    }
    // 17. loss
    loss_kernel<<<1, 256, 0, stream>>>(DIAG, ZROW, PF, PB, (float*)d_out);
}

// Round 7
// 320.856 us; speedup vs baseline: 1.3998x; 1.1865x over previous
//
#include <hip/hip_runtime.h>
#include <math.h>

#define NN_NODES 4096
#define D_IN 128
#define D_H 256
#define KTOP 17
#define NEDGE (NN_NODES * KTOP)
#define INV_TEMP 5.0f
#define EPSV 1e-8f
#define CCAP 1024

typedef __bf16 bf16x8 __attribute__((ext_vector_type(8)));
typedef float f32x4 __attribute__((ext_vector_type(4)));

// ---------------- helpers ----------------
__device__ __forceinline__ float block_reduce_sum(float v, float* sb) {
#pragma unroll
    for (int o = 32; o > 0; o >>= 1) v += __shfl_down(v, o, 64);
    int wid = threadIdx.x >> 6;
    __syncthreads();
    if ((threadIdx.x & 63) == 0) sb[wid] = v;
    __syncthreads();
    return sb[0] + sb[1] + sb[2] + sb[3];
}

// fp32 -> bf16 (RNE)
__device__ __forceinline__ unsigned short f2bf(float x) {
    unsigned u = __float_as_uint(x);
    unsigned r = u + 0x7fff + ((u >> 16) & 1);
    return (unsigned short)(r >> 16);
}

__device__ __forceinline__ float bflo(unsigned x) { return __uint_as_float(x << 16); }
__device__ __forceinline__ float bfhi(unsigned x) { return __uint_as_float(x & 0xffff0000u); }

__device__ __forceinline__ float dot8bf(uint4 a, uint4 b) {
    float s = bflo(a.x) * bflo(b.x) + bfhi(a.x) * bfhi(b.x);
    s += bflo(a.y) * bflo(b.y) + bfhi(a.y) * bfhi(b.y);
    s += bflo(a.z) * bflo(b.z) + bfhi(a.z) * bfhi(b.z);
    s += bflo(a.w) * bflo(b.w) + bfhi(a.w) * bfhi(b.w);
    return s;
}

// async global -> LDS, 16 bytes per lane (wave-uniform LDS base + lane*16)
__device__ __forceinline__ void gl_lds16(const void* g, void* l) {
    __builtin_amdgcn_global_load_lds(
        (const __attribute__((address_space(1))) void*)(g),
        (__attribute__((address_space(3))) void*)(l), 16, 0, 0);
}

#define BARRIER_SB() do { __builtin_amdgcn_s_barrier(); __builtin_amdgcn_sched_barrier(0); } while (0)
#define WAITV(n) do { asm volatile("s_waitcnt vmcnt(" #n ")" ::: "memory"); __builtin_amdgcn_sched_barrier(0); } while (0)

// ---------------- fused setup: x1 elementwise + zero(ECNT, FCNT, ZROW/PF/PB) ----------------
__global__ __launch_bounds__(256) void setup_kernel(const float* __restrict__ x,
                                                    const float* __restrict__ p_feat,
                                                    const float* __restrict__ p_shared,
                                                    float* __restrict__ x1,
                                                    int* __restrict__ ecnt,
                                                    int* __restrict__ fcnt,
                                                    float* __restrict__ zpp) {
    int i = blockIdx.x * 256 + threadIdx.x;
    if (i < NN_NODES * D_IN) {
        int c = i & (D_IN - 1);
        float v = x[i] * p_feat[c];
        v = fmaxf(v, 0.0f) * p_shared[c];
        x1[i] = v;
        return;
    }
    int z = i - NN_NODES * D_IN;
    if (z < NN_NODES) ecnt[z] = 0;
    else if (z < 2 * NN_NODES) fcnt[z - NN_NODES] = 0;
    else if (z < 5 * NN_NODES) zpp[z - 2 * NN_NODES] = 0.f;  // ZROW,PF,PB contiguous
}

// ---------------- input-graph CSR (keyed by dst) ----------------
__global__ __launch_bounds__(256) void ecount_kernel(const int* __restrict__ dst, int* __restrict__ cnt, int E) {
    int e = blockIdx.x * 256 + threadIdx.x;
    if (e < E) atomicAdd(&cnt[dst[e]], 1);
}

// exclusive scan of 4096 counts -> ptr[4097]; zeroes cnt; optional dinv=rsqrt(1+cnt)
__global__ __launch_bounds__(256) void scan_kernel(int* __restrict__ cnt, int* __restrict__ ptr,
                                                   float* __restrict__ dinv) {
    __shared__ int tmp[256];
    int t = threadIdx.x;
    int base = t * 16;
    int c[16]; int local[16]; int s = 0;
#pragma unroll
    for (int u = 0; u < 16; ++u) { c[u] = cnt[base + u]; local[u] = s; s += c[u]; cnt[base + u] = 0; }
    if (dinv) {
#pragma unroll
        for (int u = 0; u < 16; ++u) dinv[base + u] = rsqrtf(1.0f + (float)c[u]);
    }
    tmp[t] = s;
    __syncthreads();
    for (int off = 1; off < 256; off <<= 1) {
        int v = (t >= off) ? tmp[t - off] : 0;
        __syncthreads();
        tmp[t] += v;
        __syncthreads();
    }
    int prefix = (t > 0) ? tmp[t - 1] : 0;
#pragma unroll
    for (int u = 0; u < 16; ++u) ptr[base + u] = prefix + local[u];
    if (t == 255) ptr[NN_NODES] = prefix + s;
}

__global__ __launch_bounds__(256) void efill_kernel(const int* __restrict__ src, const int* __restrict__ dst,
                                                    const int* __restrict__ ptr, int* __restrict__ cnt,
                                                    int* __restrict__ esrt, int E) {
    int e = blockIdx.x * 256 + threadIdx.x;
    if (e >= E) return;
    int d = dst[e];
    int p = ptr[d] + atomicAdd(&cnt[d], 1);
    esrt[p] = src[e];
}

// ---------------- ILP gather core: acc += sum dinv[s]*dn*h[s*C+t], 8-way unrolled ----------------
template <int C>
__device__ __forceinline__ float gather_ilp(const float* __restrict__ h, const float* __restrict__ dinv,
                                            const int* __restrict__ esrt, int p, int pe,
                                            float dn, int t, float acc) {
    for (; p + 8 <= pe; p += 8) {
        int s[8];
#pragma unroll
        for (int u = 0; u < 8; ++u) s[u] = esrt[p + u];
        float dv[8];
#pragma unroll
        for (int u = 0; u < 8; ++u) dv[u] = dinv[s[u]];
        float hv[8];
#pragma unroll
        for (int u = 0; u < 8; ++u) hv[u] = h[(size_t)s[u] * C + t];
#pragma unroll
        for (int u = 0; u < 8; ++u) acc += dv[u] * dn * hv[u];
    }
    for (; p < pe; ++p) {
        int s = esrt[p];
        acc += dinv[s] * dn * h[(size_t)s * C + t];
    }
    return acc;
}

// ---------------- fused: agg gather + h/hn normalize -> bf16 ----------------
// block n, 256 threads: t<128 -> x1 part; t>=128 -> gather agg channel (t-128).
__global__ __launch_bounds__(256) void agg_hn_kernel(const float* __restrict__ x1,
                                                     const float* __restrict__ dinv,
                                                     const int* __restrict__ eptr,
                                                     const int* __restrict__ esrt,
                                                     const float* __restrict__ p_balance,
                                                     unsigned short* __restrict__ hn_bf) {
    __shared__ float sb[4];
    int n = blockIdx.x, t = threadIdx.x;
    float v;
    if (t < D_IN) {
        v = x1[(size_t)n * D_IN + t] * p_balance[t];
    } else {
        int c = t - D_IN;
        float dn = dinv[n];
        float acc = dn * dn * x1[(size_t)n * D_IN + c];
        acc = gather_ilp<D_IN>(x1, dinv, esrt, eptr[n], eptr[n + 1], dn, c, acc);
        v = acc * p_balance[t];
    }
    float ss = block_reduce_sum(v * v, sb);
    float inv = 1.0f / (sqrtf(ss) + EPSV);
    hn_bf[(size_t)n * D_H + t] = f2bf(v * inv);
}

// ---------------- fused: rownorm both Z + diag dot ----------------
__global__ __launch_bounds__(256) void rownorm_diag_kernel(const float* __restrict__ Z1,
                                                           const float* __restrict__ Z2,
                                                           unsigned short* __restrict__ z1bf,
                                                           unsigned short* __restrict__ z2bf,
                                                           float* __restrict__ diag) {
    __shared__ float sb[4];
    int n = blockIdx.x, t = threadIdx.x;
    float v1 = Z1[(size_t)n * D_H + t];
    float v2 = Z2[(size_t)n * D_H + t];
    float ss1 = block_reduce_sum(v1 * v1, sb);
    float ss2 = block_reduce_sum(v2 * v2, sb);
    float i1 = 1.0f / (sqrtf(ss1) + EPSV);
    float i2 = 1.0f / (sqrtf(ss2) + EPSV);
    z1bf[(size_t)n * D_H + t] = f2bf(v1 * i1);
    z2bf[(size_t)n * D_H + t] = f2bf(v2 * i2);
    float d = block_reduce_sum((v1 * i1) * (v2 * i2), sb);
    if (t == 0) diag[n] = d;
}

// ---------------- fp32 GEMM (small NN cases) ----------------
#define BM 64
#define BN 64
#define BK 16

__device__ __forceinline__ void gemm_nn_body(const float* __restrict__ A, const float* __restrict__ B,
                                             float* __restrict__ C, int Nn, int Kk, int m0, int n0) {
    __shared__ float As[BK][BM + 4];
    __shared__ float Bs[BK][BN + 4];
    const int tid = threadIdx.x;
    const int tx = tid & 15, ty = tid >> 4;
    const int arow = tid >> 2, acol = (tid & 3) << 2;
    const int brow = tid >> 4, bcol = (tid & 15) << 2;
    float acc[4][4] = {{0.f}};

    for (int k0 = 0; k0 < Kk; k0 += BK) {
        float4 av = *(const float4*)&A[(size_t)(m0 + arow) * Kk + k0 + acol];
        float4 bv = *(const float4*)&B[(size_t)(k0 + brow) * Nn + n0 + bcol];
        As[acol + 0][arow] = av.x;
        As[acol + 1][arow] = av.y;
        As[acol + 2][arow] = av.z;
        As[acol + 3][arow] = av.w;
        *(float4*)&Bs[brow][bcol] = bv;
        __syncthreads();
#pragma unroll
        for (int k = 0; k < BK; ++k) {
            float4 a = *(const float4*)&As[k][ty << 2];
            float4 b = *(const float4*)&Bs[k][tx << 2];
            acc[0][0] += a.x * b.x; acc[0][1] += a.x * b.y; acc[0][2] += a.x * b.z; acc[0][3] += a.x * b.w;
            acc[1][0] += a.y * b.x; acc[1][1] += a.y * b.y; acc[1][2] += a.y * b.z; acc[1][3] += a.y * b.w;
            acc[2][0] += a.z * b.x; acc[2][1] += a.z * b.y; acc[2][2] += a.z * b.z; acc[2][3] += a.z * b.w;
            acc[3][0] += a.w * b.x; acc[3][1] += a.w * b.y; acc[3][2] += a.w * b.z; acc[3][3] += a.w * b.w;
        }
        __syncthreads();
    }
#pragma unroll
    for (int i = 0; i < 4; ++i) {
        int m = m0 + (ty << 2) + i;
        *(float4*)&C[(size_t)m * Nn + n0 + (tx << 2)] = *(float4*)acc[i];
    }
}

__global__ __launch_bounds__(256) void gemm_nn_kernel(const float* __restrict__ A,
                                                      const float* __restrict__ B,
                                                      float* __restrict__ C, int Nn, int Kk) {
    gemm_nn_body(A, B, C, Nn, Kk, blockIdx.y * BM, blockIdx.x * BN);
}

// two M=4096,N=256,K=256 GEMMs in one launch (grid y doubled)
__global__ __launch_bounds__(256) void gemm_nn2x_kernel(const float* __restrict__ A1,
                                                        const float* __restrict__ A2,
                                                        const float* __restrict__ B,
                                                        float* __restrict__ C1,
                                                        float* __restrict__ C2) {
    int gy = blockIdx.y;
    const float* A = (gy < NN_NODES / BM) ? A1 : A2;
    float* C = (gy < NN_NODES / BM) ? C1 : C2;
    int m0 = (gy & (NN_NODES / BM - 1)) * BM;
    gemm_nn_body(A, B, C, D_H, D_H, m0, blockIdx.x * BN);
}

// ---------------- MFMA NT GEMM: C[4096,4096] = X @ Y^T, K=256, single bf16 ----------------
// 256x256 tile, 8 waves, BK=64, dbuf 128 KB LDS, counted-vmcnt pipeline (T4).
// MODE 0: write C. MODE 1: zrow-only (row-sums of exp(5*S)).
template <int MODE>
__global__ __launch_bounds__(512) void gemm_nt_mfma(const unsigned short* __restrict__ Abf,
                                                    const unsigned short* __restrict__ Bbf,
                                                    float* __restrict__ C,
                                                    float* __restrict__ zrow) {
    __shared__ char lds[131072];
    const int tid = threadIdx.x;
    const int w = tid >> 6, lane = tid & 63;
    const int wr = w >> 2, wc = w & 3;
    const int m0 = blockIdx.y * 256, n0 = blockIdx.x * 256;
    const int lrow = lane & 15, lquad = lane >> 4;

    f32x4 acc[8][4];
#pragma unroll
    for (int i = 0; i < 8; ++i)
#pragma unroll
        for (int j = 0; j < 4; ++j) acc[i][j] = (f32x4)(0.f);

    const char* Ag = (const char*)Abf + (size_t)m0 * 512;
    const char* Bg = (const char*)Bbf + (size_t)n0 * 512;

    const int ssub = ((lane & 7) << 4) ^ (((lane >> 3) & 7) << 4);
    auto stage = [&](int half, int k0) {
        char* Abuf = lds + half * 65536;
        char* Bbuf = Abuf + 32768;
#pragma unroll
        for (int ti = 0; ti < 4; ++ti) {
            int chunk = ti * 8 + w;
            int row = chunk * 8 + (lane >> 3);
            size_t gb = (size_t)row * 512 + (size_t)k0 * 2 + ssub;
            gl_lds16(Ag + gb, Abuf + chunk * 1024);
            gl_lds16(Bg + gb, Bbuf + chunk * 1024);
        }
    };

    auto compute = [&](int half) {
        const char* Abuf = lds + half * 65536;
        const char* Bbuf = Abuf + 32768;
#pragma unroll
        for (int ksub = 0; ksub < 2; ++ksub) {
            int co = (ksub * 64 + lquad * 16) ^ ((lrow & 7) << 4);
            bf16x8 a[8], b[4];
#pragma unroll
            for (int fi = 0; fi < 8; ++fi) {
                int row = wr * 128 + fi * 16 + lrow;
                a[fi] = __builtin_bit_cast(bf16x8, *(const uint4*)(Abuf + row * 128 + co));
            }
#pragma unroll
            for (int fj = 0; fj < 4; ++fj) {
                int row = wc * 64 + fj * 16 + lrow;
                b[fj] = __builtin_bit_cast(bf16x8, *(const uint4*)(Bbuf + row * 128 + co));
            }
#pragma unroll
            for (int fi = 0; fi < 8; ++fi)
#pragma unroll
                for (int fj = 0; fj < 4; ++fj)
                    acc[fi][fj] = __builtin_amdgcn_mfma_f32_16x16x32_bf16(a[fi], b[fj], acc[fi][fj], 0, 0, 0);
        }
    };

    stage(0, 0);
    stage(1, 64);
    WAITV(8); BARRIER_SB();
    compute(0);
    BARRIER_SB();
    stage(0, 128);
    WAITV(8); BARRIER_SB();
    compute(1);
    BARRIER_SB();
    stage(1, 192);
    WAITV(8); BARRIER_SB();
    compute(0);
    BARRIER_SB();
    WAITV(0); BARRIER_SB();
    compute(1);

    const int rq = (lane >> 4) * 4;
    if constexpr (MODE == 0) {
        const int c0 = lane & 3;
        const int cg = ((lane & 15) >> 2) << 2;
#pragma unroll
        for (int fi = 0; fi < 8; ++fi) {
            int row = m0 + wr * 128 + fi * 16 + rq + c0;
#pragma unroll
            for (int fj = 0; fj < 4; ++fj) {
                float a0 = acc[fi][fj][0], a1 = acc[fi][fj][1], a2 = acc[fi][fj][2], a3 = acc[fi][fj][3];
                float x0 = __shfl_xor(a1, 1, 64), x1 = __shfl_xor(a0, 1, 64);
                float x2 = __shfl_xor(a3, 1, 64), x3 = __shfl_xor(a2, 1, 64);
                bool odd = (c0 & 1) != 0;
                float t0 = odd ? x0 : a0;
                float t1 = odd ? a1 : x1;
                float t2 = odd ? x2 : a2;
                float t3 = odd ? a3 : x3;
                float y0 = __shfl_xor(t2, 2, 64), y2 = __shfl_xor(t0, 2, 64);
                float y1 = __shfl_xor(t3, 2, 64), y3 = __shfl_xor(t1, 2, 64);
                bool hi = (c0 & 2) != 0;
                f32x4 o;
                o[0] = hi ? y0 : t0;
                o[1] = hi ? y1 : t1;
                o[2] = hi ? t2 : y2;
                o[3] = hi ? t3 : y3;
                int cb = n0 + wc * 64 + fj * 16 + cg;
                *(f32x4*)&C[(size_t)row * NN_NODES + cb] = o;
            }
        }
    }
    if constexpr (MODE == 1) {
#pragma unroll
        for (int fi = 0; fi < 8; ++fi) {
            int rb = m0 + wr * 128 + fi * 16 + rq;
#pragma unroll
            for (int r = 0; r < 4; ++r) {
                float s = 0.f;
#pragma unroll
                for (int fj = 0; fj < 4; ++fj) s += __expf(INV_TEMP * acc[fi][fj][r]);
#pragma unroll
                for (int o = 1; o < 16; o <<= 1) s += __shfl_xor(s, o, 64);
                if ((lane & 15) == 0) atomicAdd(&zrow[rb + r], s);
            }
        }
    }
}

// ---------------- top-k (+ fused indegree count of selected indices) ----------------
__global__ __launch_bounds__(256) void topk_kernel(const float* __restrict__ S,
                                                   float* __restrict__ vals,
                                                   int* __restrict__ idxo,
                                                   int* __restrict__ fcnt) {
    __shared__ float sm[256];
    __shared__ int ccnt;
    __shared__ float cv[CCAP];
    __shared__ int ci[CCAP];
    __shared__ float wvs[8];
    __shared__ int wis[8];
    const int i = blockIdx.x, t = threadIdx.x;
    const int lane = t & 63, wid = t >> 6;
    const float* row = &S[(size_t)i * NN_NODES];
    float v[16];
    int id[16];
#pragma unroll
    for (int u = 0; u < 4; ++u) {
        int base = u * 1024 + t * 4;
        float4 f = *(const float4*)&row[base];
        v[u * 4 + 0] = f.x; id[u * 4 + 0] = base + 0;
        v[u * 4 + 1] = f.y; id[u * 4 + 1] = base + 1;
        v[u * 4 + 2] = f.z; id[u * 4 + 2] = base + 2;
        v[u * 4 + 3] = f.w; id[u * 4 + 3] = base + 3;
    }
    float m = v[0];
#pragma unroll
    for (int u = 1; u < 16; ++u) m = fmaxf(m, v[u]);
    sm[t] = m;
    if (t == 0) ccnt = 0;
    __syncthreads();

    float g = fmaxf(fmaxf(sm[lane * 4 + 0], sm[lane * 4 + 1]),
                    fmaxf(sm[lane * 4 + 2], sm[lane * 4 + 3]));
    int rank = 0;
#pragma unroll
    for (int o = 1; o < 64; ++o) {
        float ov = __shfl_xor(g, o, 64);
        int ol = lane ^ o;
        if (ov > g || (ov == g && ol < lane)) rank++;
    }
    unsigned long long ball = __ballot(rank == 16);
    int tl = __ffsll((long long)ball) - 1;
    const float T = __shfl(g, tl, 64);

#pragma unroll
    for (int u = 0; u < 16; ++u) {
        if (v[u] >= T) {
            int p = atomicAdd(&ccnt, 1);
            if (p < CCAP) { cv[p] = v[u]; ci[p] = id[u]; }
        }
    }
    __syncthreads();
    const int cnt = ccnt;

    if (cnt <= CCAP) {
        for (int p = t; p < cnt; p += 256) {
            float mv = cv[p];
            int mi = ci[p];
            int r = 0;
            for (int q = 0; q < cnt; ++q) {
                float qv = cv[q];
                int qi = ci[q];
                if (qv > mv || (qv == mv && qi < mi)) r++;
            }
            if (r < KTOP) {
                vals[i * KTOP + r] = isnan(mv) ? 0.f : mv;
                idxo[i * KTOP + r] = mi;
                atomicAdd(&fcnt[mi], 1);
            }
        }
    } else {
        float bv = v[0];
        int bi = id[0];
#pragma unroll
        for (int u = 1; u < 16; ++u)
            if (v[u] > bv || (v[u] == bv && id[u] < bi)) { bv = v[u]; bi = id[u]; }
        for (int k = 0; k < KTOP; ++k) {
            float mv = bv;
            int mi = bi;
#pragma unroll
            for (int o = 1; o < 64; o <<= 1) {
                float ov = __shfl_xor(mv, o, 64);
                int oi = __shfl_xor(mi, o, 64);
                if (ov > mv || (ov == mv && oi < mi)) { mv = ov; mi = oi; }
            }
            int slot = ((k & 1) << 2) + wid;
            if (lane == 0) { wvs[slot] = mv; wis[slot] = mi; }
            __syncthreads();
            int b0 = (k & 1) << 2;
            mv = wvs[b0]; mi = wis[b0];
#pragma unroll
            for (int ww = 1; ww < 4; ++ww) {
                float ov = wvs[b0 + ww];
                int oi = wis[b0 + ww];
                if (ov > mv || (ov == mv && oi < mi)) { mv = ov; mi = oi; }
            }
            if (t == 0) {
                vals[i * KTOP + k] = isnan(mv) ? 0.f : mv;
                idxo[i * KTOP + k] = mi;
                atomicAdd(&fcnt[mi], 1);
            }
            if (bi == mi) {
#pragma unroll
                for (int u = 0; u < 16; ++u)
                    if (id[u] == mi) v[u] = -INFINITY;
                bv = v[0]; bi = id[0];
#pragma unroll
                for (int u = 1; u < 16; ++u)
                    if (v[u] > bv || (v[u] == bv && id[u] < bi)) { bv = v[u]; bi = id[u]; }
            }
        }
    }
}

// ---------------- fused: reverse-CSR fill + fwd/rev edge weights ----------------
__global__ __launch_bounds__(256) void fillrev_wedges(const int* __restrict__ idx,
                                                      const float* __restrict__ vals,
                                                      const int* __restrict__ ptr,
                                                      int* __restrict__ fcnt,
                                                      int* __restrict__ rrow, int* __restrict__ rsrc,
                                                      float* __restrict__ wrev,
                                                      float* __restrict__ wfwd) {
    int e = blockIdx.x * 256 + threadIdx.x;
    if (e >= NEDGE) return;
    int i = e / KTOP;
    int j = idx[e];
    float a = vals[e];
    bool found = false;
    float bval = 0.f;
    const int* lj = &idx[j * KTOP];
#pragma unroll
    for (int k = 0; k < KTOP; ++k)
        if (lj[k] == i) { found = true; bval = vals[j * KTOP + k]; }
    float w = (a + (found ? bval : 0.f)) / (found ? 2.0f : 1.0f);
    wfwd[e] = w > 0.f ? w : 0.f;
    int p = ptr[j] + atomicAdd(&fcnt[j], 1);
    rrow[p] = j; rsrc[p] = i;
    wrev[p] = found ? 0.f : fmaxf(a, 0.f);
}

// ---------------- dual prop/spmm rows (one launch, grid 2*NN) ----------------
__device__ __forceinline__ void prop_row(float* __restrict__ out, const float* __restrict__ h,
                                         const float* __restrict__ dinv, const int* __restrict__ eptr,
                                         const int* __restrict__ esrt, const float* __restrict__ bias,
                                         int n, int act) {
    int t = threadIdx.x;
    float dn = dinv[n];
    float acc = dn * dn * h[(size_t)n * D_H + t];
    acc = gather_ilp<D_H>(h, dinv, esrt, eptr[n], eptr[n + 1], dn, t, acc);
    acc += bias[t];
    if (act == 1) acc = fmaxf(acc, 0.f);
    else acc = acc > 0.f ? acc : expm1f(acc);
    out[(size_t)n * D_H + t] = acc;
}

__device__ __forceinline__ void spmm_row(float* __restrict__ out, const float* __restrict__ X,
                                         const int* __restrict__ idx, const float* __restrict__ wfwd,
                                         const int* __restrict__ ptr, const int* __restrict__ rsrc,
                                         const float* __restrict__ wrev, const float* __restrict__ bias,
                                         int i, int act) {
    int c = threadIdx.x;
    float acc = 0.f;
#pragma unroll
    for (int k = 0; k < KTOP; ++k) {
        int j = idx[i * KTOP + k];
        float w = wfwd[i * KTOP + k];
        acc += w * X[(size_t)j * D_H + c];
    }
    int p = ptr[i], pe = ptr[i + 1];
    // 8-way ILP over the reverse list
    for (; p + 8 <= pe; p += 8) {
        int s[8];
        float wv[8];
#pragma unroll
        for (int u = 0; u < 8; ++u) { s[u] = rsrc[p + u]; wv[u] = wrev[p + u]; }
        float xv[8];
#pragma unroll
        for (int u = 0; u < 8; ++u) xv[u] = X[(size_t)s[u] * D_H + c];
#pragma unroll
        for (int u = 0; u < 8; ++u) acc += wv[u] * xv[u];
    }
    for (; p < pe; ++p) {
        float w = wrev[p];
        if (w != 0.f) acc += w * X[(size_t)rsrc[p] * D_H + c];
    }
    acc += bias[c];
    if (act == 1) acc = fmaxf(acc, 0.f);
    else acc = acc > 0.f ? acc : expm1f(acc);
    out[(size_t)i * D_H + c] = acc;
}

// blocks [0,NN): out1 = act(prop(Xp)); blocks [NN,2NN): out2 = act(W @ Xs)
__global__ __launch_bounds__(256) void dual_prop_spmm(const float* __restrict__ Xp,
                                                      const float* __restrict__ Xs,
                                                      const float* __restrict__ dinv,
                                                      const int* __restrict__ eptr,
                                                      const int* __restrict__ esrt,
                                                      const int* __restrict__ idx,
                                                      const float* __restrict__ wfwd,
                                                      const int* __restrict__ rptr,
                                                      const int* __restrict__ rsrc,
                                                      const float* __restrict__ wrev,
                                                      const float* __restrict__ bias,
                                                      float* __restrict__ out1,
                                                      float* __restrict__ out2,
                                                      int act) {
    int b = blockIdx.x;
    if (b < NN_NODES) prop_row(out1, Xp, dinv, eptr, esrt, bias, b, act);
    else spmm_row(out2, Xs, idx, wfwd, rptr, rsrc, wrev, bias, b - NN_NODES, act);
}

// ---------------- pf/pb (edge dots from L2-resident bf16 rows) ----------------
__global__ __launch_bounds__(256) void pfpb_edges(const unsigned short* __restrict__ z1,
                                                  const unsigned short* __restrict__ z2,
                                                  const int* __restrict__ idx,
                                                  const float* __restrict__ wfwd,
                                                  const int* __restrict__ rrow,
                                                  const int* __restrict__ rsrc,
                                                  const float* __restrict__ wrev,
                                                  const float* __restrict__ zrow,
                                                  float* __restrict__ pf, float* __restrict__ pb) {
    int g = (blockIdx.x * 256 + threadIdx.x) >> 4;
    int l = threadIdx.x & 15;
    if (g >= 2 * NEDGE) return;
    int i, j;
    float wv;
    if (g < NEDGE) { i = g / KTOP; j = idx[g]; wv = wfwd[g]; }
    else { int e2 = g - NEDGE; i = rrow[e2]; j = rsrc[e2]; wv = wrev[e2]; }
    if (wv == 0.f) return;
    const uint4* a1 = (const uint4*)&z1[(size_t)i * D_H + l * 16];
    const uint4* b1 = (const uint4*)&z2[(size_t)j * D_H + l * 16];
    const uint4* a2 = (const uint4*)&z1[(size_t)j * D_H + l * 16];
    const uint4* b2 = (const uint4*)&z2[(size_t)i * D_H + l * 16];
    float s1 = dot8bf(a1[0], b1[0]) + dot8bf(a1[1], b1[1]);
    float s2 = dot8bf(a2[0], b2[0]) + dot8bf(a2[1], b2[1]);
#pragma unroll
    for (int o = 8; o > 0; o >>= 1) {
        s1 += __shfl_xor(s1, o, 64);
        s2 += __shfl_xor(s2, o, 64);
    }
    if (l == 0) {
        float pfv = expf(s1 * INV_TEMP) / zrow[i] * wv;
        float pbv = expf(s2 * INV_TEMP) / zrow[j] * wv;
        atomicAdd(&pf[i], pfv);
        atomicAdd(&pb[i], pbv);
    }
}

__global__ __launch_bounds__(256) void loss_kernel(const float* __restrict__ diag,
                                                   const float* __restrict__ zrow,
                                                   const float* __restrict__ pf,
                                                   const float* __restrict__ pb,
                                                   float* __restrict__ out) {
    __shared__ float sb[4];
    int t = threadIdx.x;
    float s = 0.f;
    for (int i = t; i < NN_NODES; i += 256) {
        float p = expf(INV_TEMP * diag[i]) / zrow[i];
        s += -logf(fmaxf(p, EPSV));
        s += 0.5f * (-logf(fmaxf(pf[i], EPSV)) - logf(fmaxf(pb[i], EPSV)));
    }
    float tot = block_reduce_sum(s, sb);
    if (t == 0) out[0] = tot / (float)NN_NODES;
}

// ---------------- launch ----------------
extern "C" void kernel_launch(void* const* d_in, const int* in_sizes, int n_in,
                              void* d_out, int out_size, void* d_ws, size_t ws_size,
                              hipStream_t stream) {
    (void)n_in; (void)out_size; (void)ws_size;
    const float* x = (const float*)d_in[0];
    const int* esrc = (const int*)d_in[1];
    const int* edst = (const int*)d_in[2];
    const float* p_feat = (const float*)d_in[3];
    const float* p_shared = (const float*)d_in[4];
    const float* p_balance = (const float*)d_in[5];
    const float* W1 = (const float*)d_in[6];
    const float* b1 = (const float*)d_in[7];
    const float* W2 = (const float*)d_in[8];
    const float* b2 = (const float*)d_in[9];
    const int E = in_sizes[1];

    float* ws = (float*)d_ws;
    size_t off = 0;
    float* SIM = ws + off; off += (size_t)NN_NODES * NN_NODES;
    float* X1  = ws + off; off += (size_t)NN_NODES * D_IN;
    float* T1  = ws + off; off += (size_t)NN_NODES * D_H;
    float* H1  = ws + off; off += (size_t)NN_NODES * D_H;
    float* T2  = ws + off; off += (size_t)NN_NODES * D_H;
    float* T3  = ws + off; off += (size_t)NN_NODES * D_H;
    float* Z1  = ws + off; off += (size_t)NN_NODES * D_H;
    float* G1  = ws + off; off += (size_t)NN_NODES * D_H;
    float* Z2  = ws + off; off += (size_t)NN_NODES * D_H;
    float* DINV = ws + off; off += NN_NODES;
    float* VALS = ws + off; off += (size_t)NEDGE;
    int*   IDX  = (int*)(ws + off); off += (size_t)NEDGE;
    float* WFWD = ws + off; off += (size_t)NEDGE;
    int*   RPTR = (int*)(ws + off); off += NN_NODES + 1;
    int*   FCNT = (int*)(ws + off); off += NN_NODES;
    int*   RROW = (int*)(ws + off); off += (size_t)NEDGE;
    int*   RSRC = (int*)(ws + off); off += (size_t)NEDGE;
    float* WREV = ws + off; off += (size_t)NEDGE;
    float* ZROW = ws + off; off += NN_NODES;   // ZROW,PF,PB contiguous (zeroed together)
    float* PF = ws + off; off += NN_NODES;
    float* PB = ws + off; off += NN_NODES;
    float* DIAG = ws + off; off += NN_NODES;
    unsigned short* HNbf = (unsigned short*)(ws + off); off += (size_t)NN_NODES * D_H / 2;
    unsigned short* Z1bf = (unsigned short*)(ws + off); off += (size_t)NN_NODES * D_H / 2;
    unsigned short* Z2bf = (unsigned short*)(ws + off); off += (size_t)NN_NODES * D_H / 2;
    int* ECNT = (int*)(ws + off); off += NN_NODES;
    int* EPTR = (int*)(ws + off); off += NN_NODES + 1;
    int* ESRT = (int*)(ws + off); off += (size_t)E;

    const int EB = (NEDGE + 255) / 256;
    const int EBi = (E + 255) / 256;

    // 1. setup: x1 + zero(ECNT, FCNT, ZROW/PF/PB)
    {
        int blocks = (NN_NODES * D_IN + 5 * NN_NODES + 255) / 256;
        setup_kernel<<<blocks, 256, 0, stream>>>(x, p_feat, p_shared, X1, ECNT, FCNT, ZROW);
    }
    // 2. indegree count
    ecount_kernel<<<EBi, 256, 0, stream>>>(edst, ECNT, E);
    // 3. scan + dinv
    scan_kernel<<<1, 256, 0, stream>>>(ECNT, EPTR, DINV);
    // 4. CSR fill
    efill_kernel<<<EBi, 256, 0, stream>>>(esrc, edst, EPTR, ECNT, ESRT, E);
    // 5. agg gather + h/hn -> bf16
    agg_hn_kernel<<<NN_NODES, 256, 0, stream>>>(X1, DINV, EPTR, ESRT, p_balance, HNbf);
    // 6. sim = hn @ hn^T
    {
        dim3 g(NN_NODES / 256, NN_NODES / 256);
        gemm_nt_mfma<0><<<g, 512, 0, stream>>>(HNbf, HNbf, SIM, nullptr);
    }
    // 7. topk + fused indegree count of selected
    topk_kernel<<<NN_NODES, 256, 0, stream>>>(SIM, VALS, IDX, FCNT);
    // 8. scan (FCNT -> RPTR, zeroes FCNT)
    scan_kernel<<<1, 256, 0, stream>>>(FCNT, RPTR, nullptr);
    // 9. reverse fill + fwd/rev edge weights
    fillrev_wedges<<<EB, 256, 0, stream>>>(IDX, VALS, RPTR, FCNT, RROW, RSRC, WREV, WFWD);
    // 10. t1 = x1 @ W1
    {
        dim3 g(D_H / BN, NN_NODES / BM);
        gemm_nn_kernel<<<g, 256, 0, stream>>>(X1, W1, T1, D_H, D_IN);
    }
    // 11. H1 = relu(prop(T1)+b1)  ||  G1 = relu(W@T1+b1)
    dual_prop_spmm<<<2 * NN_NODES, 256, 0, stream>>>(T1, T1, DINV, EPTR, ESRT, IDX, WFWD,
                                                     RPTR, RSRC, WREV, b1, H1, G1, 1);
    // 12. T2 = H1 @ W2  ||  T3 = G1 @ W2
    {
        dim3 g(D_H / BN, 2 * NN_NODES / BM);
        gemm_nn2x_kernel<<<g, 256, 0, stream>>>(H1, G1, W2, T2, T3);
    }
    // 13. Z1 = elu(prop(T2)+b2)  ||  Z2 = elu(W@T3+b2)
    dual_prop_spmm<<<2 * NN_NODES, 256, 0, stream>>>(T2, T3, DINV, EPTR, ESRT, IDX, WFWD,
                                                     RPTR, RSRC, WREV, b2, Z1, Z2, 2);
    // 14. rownorm both -> bf16 + diag
    rownorm_diag_kernel<<<NN_NODES, 256, 0, stream>>>(Z1, Z2, Z1bf, Z2bf, DIAG);
    // 15. zrow: row-sums of exp(5 * z1n@z2n^T)
    {
        dim3 g(NN_NODES / 256, NN_NODES / 256);
        gemm_nt_mfma<1><<<g, 512, 0, stream>>>(Z1bf, Z2bf, nullptr, ZROW);
    }
    // 16. pf / pb
    {
        int blocks = (2 * NEDGE * 16 + 255) / 256;
        pfpb_edges<<<blocks, 256, 0, stream>>>(Z1bf, Z2bf, IDX, WFWD, RROW, RSRC, WREV, ZROW, PF, PB);
    }
    // 17. loss
    loss_kernel<<<1, 256, 0, stream>>>(DIAG, ZROW, PF, PB, (float*)d_out);
}